// Round 9
// baseline (319.733 us; speedup 1.0000x reference)
//
#include <hip/hip_runtime.h>
#include <hip/hip_bf16.h>

#define F_IN 64
#define HID 64
#define NCLS 10
#define NG 512

// ---------------------------------------------------------------------------
// GEMM1: x (N x 64) @ Wl1 (64 x 128) -> xl1, @ Wr1 -> xr1.
// 32-row tile, 256 threads = 8 rowgroups x 32 colgroups; 32 FMA / inner iter.
__global__ void gemm1_kernel(const float* __restrict__ x,
                             const float* __restrict__ Wl,
                             const float* __restrict__ Wr,
                             float* __restrict__ xl, float* __restrict__ xr,
                             int N_) {
    __shared__ float xs[32 * 64];
    int r0 = blockIdx.x * 32;
    int t = threadIdx.x;
    // stage x tile: 512 float4
    for (int i = t; i < 512; i += 256) {
        int row = i >> 4, c4 = i & 15;
        float4 v = make_float4(0.f, 0.f, 0.f, 0.f);
        if (r0 + row < N_) v = *(const float4*)(x + (long)(r0 + row) * 64 + c4 * 4);
        ((float4*)xs)[i] = v;
    }
    __syncthreads();
    int rg = t >> 5;   // 0..7 -> rows rg*4..+3
    int cg = t & 31;   // cols cg*4..+3
    float4 accl[4], accr[4];
#pragma unroll
    for (int r = 0; r < 4; ++r) {
        accl[r] = make_float4(0.f, 0.f, 0.f, 0.f);
        accr[r] = make_float4(0.f, 0.f, 0.f, 0.f);
    }
    for (int k = 0; k < 64; ++k) {
        float4 wl4 = *(const float4*)(Wl + k * 128 + cg * 4);
        float4 wr4 = *(const float4*)(Wr + k * 128 + cg * 4);
#pragma unroll
        for (int r = 0; r < 4; ++r) {
            float s = xs[(rg * 4 + r) * 64 + k];
            accl[r].x += s * wl4.x; accl[r].y += s * wl4.y;
            accl[r].z += s * wl4.z; accl[r].w += s * wl4.w;
            accr[r].x += s * wr4.x; accr[r].y += s * wr4.y;
            accr[r].z += s * wr4.z; accr[r].w += s * wr4.w;
        }
    }
#pragma unroll
    for (int r = 0; r < 4; ++r) {
        int row = r0 + rg * 4 + r;
        if (row < N_) {
            *(float4*)(xl + (long)row * 128 + cg * 4) = accl[r];
            *(float4*)(xr + (long)row * 128 + cg * 4) = accr[r];
        }
    }
}

// ---------------------------------------------------------------------------
// GEMM2: h1 (N x 128) @ Wl2 (128 x 64) -> xl2, @ Wr2 -> xr2.
// 32-row tile, 256 threads = 16 rowgroups x 16 colgroups; 16 FMA / inner iter.
__global__ void gemm2_kernel(const float* __restrict__ h1,
                             const float* __restrict__ Wl,
                             const float* __restrict__ Wr,
                             float* __restrict__ xl, float* __restrict__ xr,
                             int N_) {
    __shared__ float hs[32 * 128];
    int r0 = blockIdx.x * 32;
    int t = threadIdx.x;
    for (int i = t; i < 1024; i += 256) {
        int row = i >> 5, c4 = i & 31;
        float4 v = make_float4(0.f, 0.f, 0.f, 0.f);
        if (r0 + row < N_) v = *(const float4*)(h1 + (long)(r0 + row) * 128 + c4 * 4);
        ((float4*)hs)[i] = v;
    }
    __syncthreads();
    int rg = t >> 4;   // 0..15 -> rows rg*2..+1
    int cg = t & 15;   // cols cg*4..+3
    float4 accl[2], accr[2];
#pragma unroll
    for (int r = 0; r < 2; ++r) {
        accl[r] = make_float4(0.f, 0.f, 0.f, 0.f);
        accr[r] = make_float4(0.f, 0.f, 0.f, 0.f);
    }
    for (int k = 0; k < 128; ++k) {
        float4 wl4 = *(const float4*)(Wl + k * 64 + cg * 4);
        float4 wr4 = *(const float4*)(Wr + k * 64 + cg * 4);
#pragma unroll
        for (int r = 0; r < 2; ++r) {
            float s = hs[(rg * 2 + r) * 128 + k];
            accl[r].x += s * wl4.x; accl[r].y += s * wl4.y;
            accl[r].z += s * wl4.z; accl[r].w += s * wl4.w;
            accr[r].x += s * wr4.x; accr[r].y += s * wr4.y;
            accr[r].z += s * wr4.z; accr[r].w += s * wr4.w;
        }
    }
#pragma unroll
    for (int r = 0; r < 2; ++r) {
        int row = r0 + rg * 2 + r;
        if (row < N_) {
            *(float4*)(xl + (long)row * 64 + cg * 4) = accl[r];
            *(float4*)(xr + (long)row * 64 + cg * 4) = accr[r];
        }
    }
}

// ---------------------------------------------------------------------------
// CSR build: count, 3-phase device-wide scan, scatter.
__global__ void count_kernel(const int* __restrict__ ei, int* __restrict__ deg, int E_) {
    int e = blockIdx.x * 256 + threadIdx.x;
    if (e < E_) atomicAdd(&deg[ei[E_ + e]], 1);
}

__global__ void scan1_kernel(const int* __restrict__ deg, int* __restrict__ rs_part,
                             int* __restrict__ blksum, int N_) {
    __shared__ int tmp[256];
    int t = threadIdx.x;
    int i = blockIdx.x * 256 + t;
    int v = (i < N_) ? deg[i] : 0;
    tmp[t] = v;
    __syncthreads();
    for (int off = 1; off < 256; off <<= 1) {
        int add = (t >= off) ? tmp[t - off] : 0;
        __syncthreads();
        tmp[t] += add;
        __syncthreads();
    }
    if (i < N_) rs_part[i] = tmp[t] - v;
    if (t == 255) blksum[blockIdx.x] = tmp[255];
}

__global__ void scan2_kernel(int* __restrict__ blksum, int nblk) {
    __shared__ int tmp[256];
    int t = threadIdx.x;
    int v = (t < nblk) ? blksum[t] : 0;
    tmp[t] = v;
    __syncthreads();
    for (int off = 1; off < 256; off <<= 1) {
        int add = (t >= off) ? tmp[t - off] : 0;
        __syncthreads();
        tmp[t] += add;
        __syncthreads();
    }
    if (t < nblk) blksum[t] = tmp[t] - v;
}

__global__ void scan3_kernel(const int* __restrict__ rs_part,
                             const int* __restrict__ blksum,
                             int* __restrict__ rs, int* __restrict__ cursor,
                             int N_, int E_) {
    int i = blockIdx.x * 256 + threadIdx.x;
    if (i < N_) {
        int v = rs_part[i] + blksum[blockIdx.x];
        rs[i] = v;
        cursor[i] = v;
    }
    if (i == 0) rs[N_] = E_;
}

__global__ void scatter_kernel(const int* __restrict__ ei, int* __restrict__ cursor,
                               int* __restrict__ csr_src, int E_) {
    int e = blockIdx.x * 256 + threadIdx.x;
    if (e < E_) {
        int d = ei[E_ + e];
        int pos = atomicAdd(&cursor[d], 1);
        csr_src[pos] = ei[e];
    }
}

// ---------------------------------------------------------------------------
__global__ void gbound_kernel(const int* __restrict__ batch, int* __restrict__ gstart,
                              int N_) {
    int i = blockIdx.x * 256 + threadIdx.x;
    if (i >= N_) return;
    int bi = batch[i];
    int bprev = (i == 0) ? -1 : batch[i - 1];
    for (int g = bprev + 1; g <= bi; ++g) gstart[g] = i;
    if (i == N_ - 1)
        for (int g = bi + 1; g <= NG; ++g) gstart[g] = N_;
}

// ---------------------------------------------------------------------------
// Fused GATv2 layer 1, HEAD-MERGED: one wave per node covering both heads.
// Lane layout: 2 edge-slots x 32 lanes; lane holds float4 of the 128-channel
// row (ch = (lane&31)*4; ch<64 = head0, ch>=64 = head1). att/b1 index flat 128.
// Butterfly xor{1,2,4,8} reduces within 16-lane head-halves, so each half
// carries its own head's logit/weight. Step 4 edges/iter -> ~13% pad waste.
__global__ void gat1_kernel(const float* __restrict__ xl,
                            float* __restrict__ xr,   // in: xr1, out: h1
                            const float* __restrict__ att,
                            const float* __restrict__ b1,
                            const int* __restrict__ rs,
                            const int* __restrict__ csr_src,
                            int N_) {
    int d = (int)(((long)blockIdx.x * blockDim.x + threadIdx.x) >> 6);
    int lane = threadIdx.x & 63;
    if (d >= N_) return;
    int slot = lane >> 5;     // 0..1
    int c8 = lane & 31;       // channel group: channels c8*4..+3 of 128
    long rowoff = (long)d * 128 + c8 * 4;
    const float4 xr4 = *(const float4*)(xr + rowoff);
    const float4 at4 = *(const float4*)(att + c8 * 4);

    int k0 = rs[d], k1 = rs[d + 1];
    int cnt = k1 - k0 + 1;    // virtual edges incl. self (slot 0)

    float4 acc = make_float4(0.f, 0.f, 0.f, 0.f);
    float den = 0.f;
    for (int c0 = 0; c0 < cnt; c0 += 64) {
        int wl = c0 + lane;
        int myidx = (wl >= 1 && wl < cnt) ? csr_src[k0 + wl - 1] : d;
        int lim = min(64, cnt - c0);
        for (int p = 0; p < lim; p += 4) {
            int e0 = p + slot, e1 = p + 2 + slot;
            int s0 = __shfl(myidx, e0, 64);
            int s1 = __shfl(myidx, e1, 64);
            bool v0 = e0 < lim, v1 = e1 < lim;
            float4 a0 = *(const float4*)(xl + (long)s0 * 128 + c8 * 4);
            float4 a1 = *(const float4*)(xl + (long)s1 * 128 + c8 * 4);
            float t, p0, p1;
            t = a0.x + xr4.x; t = fmaxf(t, 0.2f * t); p0  = at4.x * t;
            t = a0.y + xr4.y; t = fmaxf(t, 0.2f * t); p0 += at4.y * t;
            t = a0.z + xr4.z; t = fmaxf(t, 0.2f * t); p0 += at4.z * t;
            t = a0.w + xr4.w; t = fmaxf(t, 0.2f * t); p0 += at4.w * t;
            t = a1.x + xr4.x; t = fmaxf(t, 0.2f * t); p1  = at4.x * t;
            t = a1.y + xr4.y; t = fmaxf(t, 0.2f * t); p1 += at4.y * t;
            t = a1.z + xr4.z; t = fmaxf(t, 0.2f * t); p1 += at4.z * t;
            t = a1.w + xr4.w; t = fmaxf(t, 0.2f * t); p1 += at4.w * t;
            p0 += __shfl_xor(p0, 1, 64);  p1 += __shfl_xor(p1, 1, 64);
            p0 += __shfl_xor(p0, 2, 64);  p1 += __shfl_xor(p1, 2, 64);
            p0 += __shfl_xor(p0, 4, 64);  p1 += __shfl_xor(p1, 4, 64);
            p0 += __shfl_xor(p0, 8, 64);  p1 += __shfl_xor(p1, 8, 64);
            float w0 = v0 ? __expf(p0) : 0.f;
            float w1 = v1 ? __expf(p1) : 0.f;
            acc.x += w0 * a0.x + w1 * a1.x;
            acc.y += w0 * a0.y + w1 * a1.y;
            acc.z += w0 * a0.z + w1 * a1.z;
            acc.w += w0 * a0.w + w1 * a1.w;
            den += w0 + w1;
        }
    }
    // combine the two edge-slots (same channel+head across xor 32)
    acc.x += __shfl_xor(acc.x, 32, 64);
    acc.y += __shfl_xor(acc.y, 32, 64);
    acc.z += __shfl_xor(acc.z, 32, 64);
    acc.w += __shfl_xor(acc.w, 32, 64);
    den   += __shfl_xor(den, 32, 64);
    if (slot == 0) {
        const float4 b4 = *(const float4*)(b1 + c8 * 4);
        float inv = 1.f / den;
        float4 v;
        v.x = acc.x * inv + b4.x; v.x = (v.x > 0.f) ? v.x : __expf(v.x) - 1.f;
        v.y = acc.y * inv + b4.y; v.y = (v.y > 0.f) ? v.y : __expf(v.y) - 1.f;
        v.z = acc.z * inv + b4.z; v.z = (v.z > 0.f) ? v.z : __expf(v.z) - 1.f;
        v.w = acc.w * inv + b4.w; v.w = (v.w > 0.f) ? v.w : __expf(v.w) - 1.f;
        *(float4*)(xr + rowoff) = v;   // h1 in place
    }
}

// ---------------------------------------------------------------------------
// Fused GATv2 layer 2 (H=1, C=64): writes h2 row (no atomics).
__global__ void gat2_kernel(const float* __restrict__ xl,
                            const float* __restrict__ xr,
                            const float* __restrict__ att,
                            const float* __restrict__ b2,
                            const int* __restrict__ rs,
                            const int* __restrict__ csr_src,
                            float* __restrict__ h2,
                            int N_) {
    int d = (int)(((long)blockIdx.x * blockDim.x + threadIdx.x) >> 6);
    int lane = threadIdx.x & 63;
    if (d >= N_) return;
    int g = lane >> 4;
    int c4 = lane & 15;
    long rowoff = (long)d * 64 + c4 * 4;
    const float4 xr4 = *(const float4*)(xr + rowoff);
    const float4 at4 = *(const float4*)(att + c4 * 4);

    int k0 = rs[d], k1 = rs[d + 1];
    int cnt = k1 - k0 + 1;

    float4 acc = make_float4(0.f, 0.f, 0.f, 0.f);
    float den = 0.f;
    for (int c0 = 0; c0 < cnt; c0 += 64) {
        int wl = c0 + lane;
        int myidx = (wl >= 1 && wl < cnt) ? csr_src[k0 + wl - 1] : d;
        int lim = min(64, cnt - c0);
        for (int p = 0; p < lim; p += 8) {
            int e0 = p + g, e1 = p + 4 + g;
            int s0 = __shfl(myidx, e0, 64);
            int s1 = __shfl(myidx, e1, 64);
            bool v0 = e0 < lim, v1 = e1 < lim;
            float4 a0 = *(const float4*)(xl + (long)s0 * 64 + c4 * 4);
            float4 a1 = *(const float4*)(xl + (long)s1 * 64 + c4 * 4);
            float t, p0, p1;
            t = a0.x + xr4.x; t = fmaxf(t, 0.2f * t); p0  = at4.x * t;
            t = a0.y + xr4.y; t = fmaxf(t, 0.2f * t); p0 += at4.y * t;
            t = a0.z + xr4.z; t = fmaxf(t, 0.2f * t); p0 += at4.z * t;
            t = a0.w + xr4.w; t = fmaxf(t, 0.2f * t); p0 += at4.w * t;
            t = a1.x + xr4.x; t = fmaxf(t, 0.2f * t); p1  = at4.x * t;
            t = a1.y + xr4.y; t = fmaxf(t, 0.2f * t); p1 += at4.y * t;
            t = a1.z + xr4.z; t = fmaxf(t, 0.2f * t); p1 += at4.z * t;
            t = a1.w + xr4.w; t = fmaxf(t, 0.2f * t); p1 += at4.w * t;
            p0 += __shfl_xor(p0, 1, 64);  p1 += __shfl_xor(p1, 1, 64);
            p0 += __shfl_xor(p0, 2, 64);  p1 += __shfl_xor(p1, 2, 64);
            p0 += __shfl_xor(p0, 4, 64);  p1 += __shfl_xor(p1, 4, 64);
            p0 += __shfl_xor(p0, 8, 64);  p1 += __shfl_xor(p1, 8, 64);
            float w0 = v0 ? __expf(p0) : 0.f;
            float w1 = v1 ? __expf(p1) : 0.f;
            acc.x += w0 * a0.x + w1 * a1.x;
            acc.y += w0 * a0.y + w1 * a1.y;
            acc.z += w0 * a0.z + w1 * a1.z;
            acc.w += w0 * a0.w + w1 * a1.w;
            den += w0 + w1;
        }
    }
#pragma unroll
    for (int m = 16; m < 64; m <<= 1) {
        acc.x += __shfl_xor(acc.x, m, 64);
        acc.y += __shfl_xor(acc.y, m, 64);
        acc.z += __shfl_xor(acc.z, m, 64);
        acc.w += __shfl_xor(acc.w, m, 64);
        den   += __shfl_xor(den, m, 64);
    }
    if (g == 0) {
        const float4 b4 = *(const float4*)(b2 + c4 * 4);
        float inv = 1.f / den;
        float4 v;
        v.x = acc.x * inv + b4.x;
        v.y = acc.y * inv + b4.y;
        v.z = acc.z * inv + b4.z;
        v.w = acc.w * inv + b4.w;
        *(float4*)(h2 + rowoff) = v;
    }
}

// ---------------------------------------------------------------------------
// Segmented mean-pool over sorted batch ranges + 64x10 classifier.
__global__ void pool_final_kernel(const float* __restrict__ h2,
                                  const int* __restrict__ gstart,
                                  const float* __restrict__ lin_w,
                                  const float* __restrict__ lin_b,
                                  float* __restrict__ out) {
    int g = blockIdx.x;
    int lane = threadIdx.x;
    int s = gstart[g], e = gstart[g + 1];
    float acc = 0.f;
    int i = s;
    for (; i + 3 < e; i += 4) {
        float v0 = h2[(long)i * 64 + lane];
        float v1 = h2[(long)(i + 1) * 64 + lane];
        float v2 = h2[(long)(i + 2) * 64 + lane];
        float v3 = h2[(long)(i + 3) * 64 + lane];
        acc += (v0 + v1) + (v2 + v3);
    }
    for (; i < e; ++i) acc += h2[(long)i * 64 + lane];
    float pc = acc / fmaxf((float)(e - s), 1.f);
    __shared__ float pl[64];
    pl[lane] = pc;
    __syncthreads();
    if (lane < NCLS) {
        float o = lin_b[lane];
#pragma unroll 8
        for (int c = 0; c < 64; ++c) o += pl[c] * lin_w[c * NCLS + lane];
        out[g * NCLS + lane] = o;
    }
}

// ---------------------------------------------------------------------------
extern "C" void kernel_launch(void* const* d_in, const int* in_sizes, int n_in,
                              void* d_out, int out_size, void* d_ws, size_t ws_size,
                              hipStream_t stream) {
    const float* x     = (const float*)d_in[0];
    const int*   ei    = (const int*)d_in[1];
    const int*   batch = (const int*)d_in[2];
    const float* Wl1   = (const float*)d_in[3];
    const float* Wr1   = (const float*)d_in[4];
    const float* att1  = (const float*)d_in[5];
    const float* b1    = (const float*)d_in[6];
    const float* Wl2   = (const float*)d_in[7];
    const float* Wr2   = (const float*)d_in[8];
    const float* att2  = (const float*)d_in[9];
    const float* b2    = (const float*)d_in[10];
    const float* lin_w = (const float*)d_in[11];
    const float* lin_b = (const float*)d_in[12];
    float* out = (float*)d_out;

    const int N_ = in_sizes[0] / F_IN;   // 50000
    const int E_ = in_sizes[1] / 2;      // 800000

    // Workspace layout
    float* ws = (float*)d_ws;
    float* A = ws;                        // xl1 (N x 128); later xl2|xr2
    float* B = A + (long)N_ * 128;        // xr1 -> h1 in place; later h2 (N x 64)
    int* deg     = (int*)(B + (long)N_ * 128);  // N
    int* rs      = deg + N_;              // N+1
    int* cursor  = rs + N_ + 1;           // N
    int* csr_src = cursor + N_;           // E
    int* gstart  = csr_src + E_;          // NG+1
    int* rs_part = gstart + NG + 1;       // N
    int* blksum  = rs_part + N_;          // 256
    float* xl2 = A;
    float* xr2 = A + (long)N_ * 64;
    float* h2  = B;

    const int nblk = (N_ + 255) / 256;   // 196 for N=50000 (must be <= 256)

    // --- CSR build + graph bounds ---
    hipMemsetAsync(deg, 0, (size_t)N_ * sizeof(int), stream);
    count_kernel<<<(E_ + 255) / 256, 256, 0, stream>>>(ei, deg, E_);
    gbound_kernel<<<(N_ + 255) / 256, 256, 0, stream>>>(batch, gstart, N_);
    scan1_kernel<<<nblk, 256, 0, stream>>>(deg, rs_part, blksum, N_);
    scan2_kernel<<<1, 256, 0, stream>>>(blksum, nblk);
    scan3_kernel<<<nblk, 256, 0, stream>>>(rs_part, blksum, rs, cursor, N_, E_);
    scatter_kernel<<<(E_ + 255) / 256, 256, 0, stream>>>(ei, cursor, csr_src, E_);

    // --- layer 1 ---
    gemm1_kernel<<<(N_ + 31) / 32, 256, 0, stream>>>(x, Wl1, Wr1, A, B, N_);
    {
        int blocks = (int)(((long)N_ * 64 + 255) / 256);
        gat1_kernel<<<blocks, 256, 0, stream>>>(A, B, att1, b1, rs, csr_src, N_);
    }

    // --- layer 2 ---
    gemm2_kernel<<<(N_ + 31) / 32, 256, 0, stream>>>(B, Wl2, Wr2, xl2, xr2, N_);
    {
        int blocks = (int)(((long)N_ * 64 + 255) / 256);
        gat2_kernel<<<blocks, 256, 0, stream>>>(xl2, xr2, att2, b2, rs, csr_src, h2, N_);
    }

    // --- pooling + classifier (segmented, atomic-free) ---
    pool_final_kernel<<<NG, 64, 0, stream>>>(h2, gstart, lin_w, lin_b, out);
}

// Round 10
// 297.103 us; speedup vs baseline: 1.0762x; 1.0762x over previous
//
#include <hip/hip_runtime.h>
#include <hip/hip_bf16.h>

#define F_IN 64
#define HID 64
#define NCLS 10
#define NG 512

// ---------------------------------------------------------------------------
// GEMM1: x (N x 64) @ Wl1 (64 x 128) -> xl1, @ Wr1 -> xr1.  (round-8 version)
__global__ void gemm1_kernel(const float* __restrict__ x,
                             const float* __restrict__ Wl,
                             const float* __restrict__ Wr,
                             float* __restrict__ xl, float* __restrict__ xr,
                             int N_) {
    __shared__ float xs[8 * 64];
    int r0 = blockIdx.x * 8;
    int t = threadIdx.x;
    for (int i = t; i < 8 * 64; i += 256) {
        int r = i >> 6;
        xs[i] = (r0 + r < N_) ? x[(long)(r0 + r) * 64 + (i & 63)] : 0.f;
    }
    __syncthreads();
    const float* W = (t < 128) ? Wl : Wr;
    int col = t & 127;
    float acc[8] = {0.f, 0.f, 0.f, 0.f, 0.f, 0.f, 0.f, 0.f};
    for (int k = 0; k < 64; ++k) {
        float w = W[k * 128 + col];
#pragma unroll
        for (int r = 0; r < 8; ++r) acc[r] += xs[r * 64 + k] * w;
    }
    float* out = (t < 128) ? xl : xr;
#pragma unroll
    for (int r = 0; r < 8; ++r)
        if (r0 + r < N_) out[(long)(r0 + r) * 128 + col] = acc[r];
}

// ---------------------------------------------------------------------------
// GEMM2: h1 (N x 128) @ Wl2 (128 x 64) -> xl2, @ Wr2 -> xr2.  (round-8 version)
__global__ void gemm2_kernel(const float* __restrict__ h1,
                             const float* __restrict__ Wl,
                             const float* __restrict__ Wr,
                             float* __restrict__ xl, float* __restrict__ xr,
                             int N_) {
    __shared__ float hs[8 * 128];
    int r0 = blockIdx.x * 8;
    int t = threadIdx.x;
    for (int i = t; i < 8 * 128; i += 128) {
        int r = i >> 7;
        hs[i] = (r0 + r < N_) ? h1[(long)(r0 + r) * 128 + (i & 127)] : 0.f;
    }
    __syncthreads();
    const float* W = (t < 64) ? Wl : Wr;
    int col = t & 63;
    float acc[8] = {0.f, 0.f, 0.f, 0.f, 0.f, 0.f, 0.f, 0.f};
    for (int k = 0; k < 128; ++k) {
        float w = W[k * 64 + col];
#pragma unroll
        for (int r = 0; r < 8; ++r) acc[r] += hs[r * 128 + k] * w;
    }
    float* out = (t < 64) ? xl : xr;
#pragma unroll
    for (int r = 0; r < 8; ++r)
        if (r0 + r < N_) out[(long)(r0 + r) * 64 + col] = acc[r];
}

// ---------------------------------------------------------------------------
// CSR build: count, 3-phase device-wide scan, scatter.
__global__ void count_kernel(const int* __restrict__ ei, int* __restrict__ deg, int E_) {
    int e = blockIdx.x * 256 + threadIdx.x;
    if (e < E_) atomicAdd(&deg[ei[E_ + e]], 1);
}

__global__ void scan1_kernel(const int* __restrict__ deg, int* __restrict__ rs_part,
                             int* __restrict__ blksum, int N_) {
    __shared__ int tmp[256];
    int t = threadIdx.x;
    int i = blockIdx.x * 256 + t;
    int v = (i < N_) ? deg[i] : 0;
    tmp[t] = v;
    __syncthreads();
    for (int off = 1; off < 256; off <<= 1) {
        int add = (t >= off) ? tmp[t - off] : 0;
        __syncthreads();
        tmp[t] += add;
        __syncthreads();
    }
    if (i < N_) rs_part[i] = tmp[t] - v;
    if (t == 255) blksum[blockIdx.x] = tmp[255];
}

__global__ void scan2_kernel(int* __restrict__ blksum, int nblk) {
    __shared__ int tmp[256];
    int t = threadIdx.x;
    int v = (t < nblk) ? blksum[t] : 0;
    tmp[t] = v;
    __syncthreads();
    for (int off = 1; off < 256; off <<= 1) {
        int add = (t >= off) ? tmp[t - off] : 0;
        __syncthreads();
        tmp[t] += add;
        __syncthreads();
    }
    if (t < nblk) blksum[t] = tmp[t] - v;
}

__global__ void scan3_kernel(const int* __restrict__ rs_part,
                             const int* __restrict__ blksum,
                             int* __restrict__ rs, int* __restrict__ cursor,
                             int N_, int E_) {
    int i = blockIdx.x * 256 + threadIdx.x;
    if (i < N_) {
        int v = rs_part[i] + blksum[blockIdx.x];
        rs[i] = v;
        cursor[i] = v;
    }
    if (i == 0) rs[N_] = E_;
}

__global__ void scatter_kernel(const int* __restrict__ ei, int* __restrict__ cursor,
                               int* __restrict__ csr_src, int E_) {
    int e = blockIdx.x * 256 + threadIdx.x;
    if (e < E_) {
        int d = ei[E_ + e];
        int pos = atomicAdd(&cursor[d], 1);
        csr_src[pos] = ei[e];
    }
}

// ---------------------------------------------------------------------------
__global__ void gbound_kernel(const int* __restrict__ batch, int* __restrict__ gstart,
                              int N_) {
    int i = blockIdx.x * 256 + threadIdx.x;
    if (i >= N_) return;
    int bi = batch[i];
    int bprev = (i == 0) ? -1 : batch[i - 1];
    for (int g = bprev + 1; g <= bi; ++g) gstart[g] = i;
    if (i == N_ - 1)
        for (int g = bi + 1; g <= NG; ++g) gstart[g] = N_;
}

// ---------------------------------------------------------------------------
// Fused GATv2 layer 1, HEAD-MERGED: one wave per node covering both heads.
// Lane layout: 2 edge-slots x 32 lanes; lane holds float4 of the 128-channel
// row (ch = (lane&31)*4; ch<64 = head0, ch>=64 = head1). att/b1 index flat 128.
// Butterfly xor{1,2,4,8} reduces within 16-lane head-halves, so each half
// carries its own head's logit/weight. Step 4 edges/iter -> ~13% pad waste.
__global__ void gat1_kernel(const float* __restrict__ xl,
                            float* __restrict__ xr,   // in: xr1, out: h1
                            const float* __restrict__ att,
                            const float* __restrict__ b1,
                            const int* __restrict__ rs,
                            const int* __restrict__ csr_src,
                            int N_) {
    int d = (int)(((long)blockIdx.x * blockDim.x + threadIdx.x) >> 6);
    int lane = threadIdx.x & 63;
    if (d >= N_) return;
    int slot = lane >> 5;     // 0..1
    int c8 = lane & 31;       // channel group: channels c8*4..+3 of 128
    long rowoff = (long)d * 128 + c8 * 4;
    const float4 xr4 = *(const float4*)(xr + rowoff);
    const float4 at4 = *(const float4*)(att + c8 * 4);

    int k0 = rs[d], k1 = rs[d + 1];
    int cnt = k1 - k0 + 1;    // virtual edges incl. self (slot 0)

    float4 acc = make_float4(0.f, 0.f, 0.f, 0.f);
    float den = 0.f;
    for (int c0 = 0; c0 < cnt; c0 += 64) {
        int wl = c0 + lane;
        int myidx = (wl >= 1 && wl < cnt) ? csr_src[k0 + wl - 1] : d;
        int lim = min(64, cnt - c0);
        for (int p = 0; p < lim; p += 4) {
            int e0 = p + slot, e1 = p + 2 + slot;
            int s0 = __shfl(myidx, e0, 64);
            int s1 = __shfl(myidx, e1, 64);
            bool v0 = e0 < lim, v1 = e1 < lim;
            float4 a0 = *(const float4*)(xl + (long)s0 * 128 + c8 * 4);
            float4 a1 = *(const float4*)(xl + (long)s1 * 128 + c8 * 4);
            float t, p0, p1;
            t = a0.x + xr4.x; t = fmaxf(t, 0.2f * t); p0  = at4.x * t;
            t = a0.y + xr4.y; t = fmaxf(t, 0.2f * t); p0 += at4.y * t;
            t = a0.z + xr4.z; t = fmaxf(t, 0.2f * t); p0 += at4.z * t;
            t = a0.w + xr4.w; t = fmaxf(t, 0.2f * t); p0 += at4.w * t;
            t = a1.x + xr4.x; t = fmaxf(t, 0.2f * t); p1  = at4.x * t;
            t = a1.y + xr4.y; t = fmaxf(t, 0.2f * t); p1 += at4.y * t;
            t = a1.z + xr4.z; t = fmaxf(t, 0.2f * t); p1 += at4.z * t;
            t = a1.w + xr4.w; t = fmaxf(t, 0.2f * t); p1 += at4.w * t;
            p0 += __shfl_xor(p0, 1, 64);  p1 += __shfl_xor(p1, 1, 64);
            p0 += __shfl_xor(p0, 2, 64);  p1 += __shfl_xor(p1, 2, 64);
            p0 += __shfl_xor(p0, 4, 64);  p1 += __shfl_xor(p1, 4, 64);
            p0 += __shfl_xor(p0, 8, 64);  p1 += __shfl_xor(p1, 8, 64);
            float w0 = v0 ? __expf(p0) : 0.f;
            float w1 = v1 ? __expf(p1) : 0.f;
            acc.x += w0 * a0.x + w1 * a1.x;
            acc.y += w0 * a0.y + w1 * a1.y;
            acc.z += w0 * a0.z + w1 * a1.z;
            acc.w += w0 * a0.w + w1 * a1.w;
            den += w0 + w1;
        }
    }
    // combine the two edge-slots (same channel+head across xor 32)
    acc.x += __shfl_xor(acc.x, 32, 64);
    acc.y += __shfl_xor(acc.y, 32, 64);
    acc.z += __shfl_xor(acc.z, 32, 64);
    acc.w += __shfl_xor(acc.w, 32, 64);
    den   += __shfl_xor(den, 32, 64);
    if (slot == 0) {
        const float4 b4 = *(const float4*)(b1 + c8 * 4);
        float inv = 1.f / den;
        float4 v;
        v.x = acc.x * inv + b4.x; v.x = (v.x > 0.f) ? v.x : __expf(v.x) - 1.f;
        v.y = acc.y * inv + b4.y; v.y = (v.y > 0.f) ? v.y : __expf(v.y) - 1.f;
        v.z = acc.z * inv + b4.z; v.z = (v.z > 0.f) ? v.z : __expf(v.z) - 1.f;
        v.w = acc.w * inv + b4.w; v.w = (v.w > 0.f) ? v.w : __expf(v.w) - 1.f;
        *(float4*)(xr + rowoff) = v;   // h1 in place
    }
}

// ---------------------------------------------------------------------------
// Fused GATv2 layer 2 (H=1, C=64): writes h2 row (no atomics).
__global__ void gat2_kernel(const float* __restrict__ xl,
                            const float* __restrict__ xr,
                            const float* __restrict__ att,
                            const float* __restrict__ b2,
                            const int* __restrict__ rs,
                            const int* __restrict__ csr_src,
                            float* __restrict__ h2,
                            int N_) {
    int d = (int)(((long)blockIdx.x * blockDim.x + threadIdx.x) >> 6);
    int lane = threadIdx.x & 63;
    if (d >= N_) return;
    int g = lane >> 4;
    int c4 = lane & 15;
    long rowoff = (long)d * 64 + c4 * 4;
    const float4 xr4 = *(const float4*)(xr + rowoff);
    const float4 at4 = *(const float4*)(att + c4 * 4);

    int k0 = rs[d], k1 = rs[d + 1];
    int cnt = k1 - k0 + 1;

    float4 acc = make_float4(0.f, 0.f, 0.f, 0.f);
    float den = 0.f;
    for (int c0 = 0; c0 < cnt; c0 += 64) {
        int wl = c0 + lane;
        int myidx = (wl >= 1 && wl < cnt) ? csr_src[k0 + wl - 1] : d;
        int lim = min(64, cnt - c0);
        for (int p = 0; p < lim; p += 8) {
            int e0 = p + g, e1 = p + 4 + g;
            int s0 = __shfl(myidx, e0, 64);
            int s1 = __shfl(myidx, e1, 64);
            bool v0 = e0 < lim, v1 = e1 < lim;
            float4 a0 = *(const float4*)(xl + (long)s0 * 64 + c4 * 4);
            float4 a1 = *(const float4*)(xl + (long)s1 * 64 + c4 * 4);
            float t, p0, p1;
            t = a0.x + xr4.x; t = fmaxf(t, 0.2f * t); p0  = at4.x * t;
            t = a0.y + xr4.y; t = fmaxf(t, 0.2f * t); p0 += at4.y * t;
            t = a0.z + xr4.z; t = fmaxf(t, 0.2f * t); p0 += at4.z * t;
            t = a0.w + xr4.w; t = fmaxf(t, 0.2f * t); p0 += at4.w * t;
            t = a1.x + xr4.x; t = fmaxf(t, 0.2f * t); p1  = at4.x * t;
            t = a1.y + xr4.y; t = fmaxf(t, 0.2f * t); p1 += at4.y * t;
            t = a1.z + xr4.z; t = fmaxf(t, 0.2f * t); p1 += at4.z * t;
            t = a1.w + xr4.w; t = fmaxf(t, 0.2f * t); p1 += at4.w * t;
            p0 += __shfl_xor(p0, 1, 64);  p1 += __shfl_xor(p1, 1, 64);
            p0 += __shfl_xor(p0, 2, 64);  p1 += __shfl_xor(p1, 2, 64);
            p0 += __shfl_xor(p0, 4, 64);  p1 += __shfl_xor(p1, 4, 64);
            p0 += __shfl_xor(p0, 8, 64);  p1 += __shfl_xor(p1, 8, 64);
            float w0 = v0 ? __expf(p0) : 0.f;
            float w1 = v1 ? __expf(p1) : 0.f;
            acc.x += w0 * a0.x + w1 * a1.x;
            acc.y += w0 * a0.y + w1 * a1.y;
            acc.z += w0 * a0.z + w1 * a1.z;
            acc.w += w0 * a0.w + w1 * a1.w;
            den += w0 + w1;
        }
    }
#pragma unroll
    for (int m = 16; m < 64; m <<= 1) {
        acc.x += __shfl_xor(acc.x, m, 64);
        acc.y += __shfl_xor(acc.y, m, 64);
        acc.z += __shfl_xor(acc.z, m, 64);
        acc.w += __shfl_xor(acc.w, m, 64);
        den   += __shfl_xor(den, m, 64);
    }
    if (g == 0) {
        const float4 b4 = *(const float4*)(b2 + c4 * 4);
        float inv = 1.f / den;
        float4 v;
        v.x = acc.x * inv + b4.x;
        v.y = acc.y * inv + b4.y;
        v.z = acc.z * inv + b4.z;
        v.w = acc.w * inv + b4.w;
        *(float4*)(h2 + rowoff) = v;
    }
}

// ---------------------------------------------------------------------------
// Segmented mean-pool over sorted batch ranges + 64x10 classifier.
__global__ void pool_final_kernel(const float* __restrict__ h2,
                                  const int* __restrict__ gstart,
                                  const float* __restrict__ lin_w,
                                  const float* __restrict__ lin_b,
                                  float* __restrict__ out) {
    int g = blockIdx.x;
    int lane = threadIdx.x;
    int s = gstart[g], e = gstart[g + 1];
    float acc = 0.f;
    int i = s;
    for (; i + 3 < e; i += 4) {
        float v0 = h2[(long)i * 64 + lane];
        float v1 = h2[(long)(i + 1) * 64 + lane];
        float v2 = h2[(long)(i + 2) * 64 + lane];
        float v3 = h2[(long)(i + 3) * 64 + lane];
        acc += (v0 + v1) + (v2 + v3);
    }
    for (; i < e; ++i) acc += h2[(long)i * 64 + lane];
    float pc = acc / fmaxf((float)(e - s), 1.f);
    __shared__ float pl[64];
    pl[lane] = pc;
    __syncthreads();
    if (lane < NCLS) {
        float o = lin_b[lane];
#pragma unroll 8
        for (int c = 0; c < 64; ++c) o += pl[c] * lin_w[c * NCLS + lane];
        out[g * NCLS + lane] = o;
    }
}

// ---------------------------------------------------------------------------
extern "C" void kernel_launch(void* const* d_in, const int* in_sizes, int n_in,
                              void* d_out, int out_size, void* d_ws, size_t ws_size,
                              hipStream_t stream) {
    const float* x     = (const float*)d_in[0];
    const int*   ei    = (const int*)d_in[1];
    const int*   batch = (const int*)d_in[2];
    const float* Wl1   = (const float*)d_in[3];
    const float* Wr1   = (const float*)d_in[4];
    const float* att1  = (const float*)d_in[5];
    const float* b1    = (const float*)d_in[6];
    const float* Wl2   = (const float*)d_in[7];
    const float* Wr2   = (const float*)d_in[8];
    const float* att2  = (const float*)d_in[9];
    const float* b2    = (const float*)d_in[10];
    const float* lin_w = (const float*)d_in[11];
    const float* lin_b = (const float*)d_in[12];
    float* out = (float*)d_out;

    const int N_ = in_sizes[0] / F_IN;   // 50000
    const int E_ = in_sizes[1] / 2;      // 800000

    // Workspace layout
    float* ws = (float*)d_ws;
    float* A = ws;                        // xl1 (N x 128); later xl2|xr2
    float* B = A + (long)N_ * 128;        // xr1 -> h1 in place; later h2 (N x 64)
    int* deg     = (int*)(B + (long)N_ * 128);  // N
    int* rs      = deg + N_;              // N+1
    int* cursor  = rs + N_ + 1;           // N
    int* csr_src = cursor + N_;           // E
    int* gstart  = csr_src + E_;          // NG+1
    int* rs_part = gstart + NG + 1;       // N
    int* blksum  = rs_part + N_;          // 256
    float* xl2 = A;
    float* xr2 = A + (long)N_ * 64;
    float* h2  = B;

    const int nblk = (N_ + 255) / 256;   // 196 for N=50000 (must be <= 256)

    // --- CSR build + graph bounds ---
    hipMemsetAsync(deg, 0, (size_t)N_ * sizeof(int), stream);
    count_kernel<<<(E_ + 255) / 256, 256, 0, stream>>>(ei, deg, E_);
    gbound_kernel<<<(N_ + 255) / 256, 256, 0, stream>>>(batch, gstart, N_);
    scan1_kernel<<<nblk, 256, 0, stream>>>(deg, rs_part, blksum, N_);
    scan2_kernel<<<1, 256, 0, stream>>>(blksum, nblk);
    scan3_kernel<<<nblk, 256, 0, stream>>>(rs_part, blksum, rs, cursor, N_, E_);
    scatter_kernel<<<(E_ + 255) / 256, 256, 0, stream>>>(ei, cursor, csr_src, E_);

    // --- layer 1 ---
    gemm1_kernel<<<(N_ + 7) / 8, 256, 0, stream>>>(x, Wl1, Wr1, A, B, N_);
    {
        int blocks = (int)(((long)N_ * 64 + 255) / 256);
        gat1_kernel<<<blocks, 256, 0, stream>>>(A, B, att1, b1, rs, csr_src, N_);
    }

    // --- layer 2 ---
    gemm2_kernel<<<(N_ + 7) / 8, 128, 0, stream>>>(B, Wl2, Wr2, xl2, xr2, N_);
    {
        int blocks = (int)(((long)N_ * 64 + 255) / 256);
        gat2_kernel<<<blocks, 256, 0, stream>>>(xl2, xr2, att2, b2, rs, csr_src, h2, N_);
    }

    // --- pooling + classifier (segmented, atomic-free) ---
    pool_final_kernel<<<NG, 64, 0, stream>>>(h2, gstart, lin_w, lin_b, out);
}

// Round 11
// 290.520 us; speedup vs baseline: 1.1006x; 1.0227x over previous
//
#include <hip/hip_runtime.h>
#include <hip/hip_bf16.h>

#define F_IN 64
#define HID 64
#define NCLS 10
#define NG 512

// ---------------------------------------------------------------------------
// Fused: count (blocks [0, cblk)) + gbound (blocks [cblk, cblk+gblk)).
__global__ void count_gbound_kernel(const int* __restrict__ ei, int* __restrict__ deg,
                                    const int* __restrict__ batch, int* __restrict__ gstart,
                                    int E_, int N_, int cblk) {
    int b = blockIdx.x;
    if (b < cblk) {
        int e = b * 256 + threadIdx.x;
        if (e < E_) atomicAdd(&deg[ei[E_ + e]], 1);
    } else {
        int i = (b - cblk) * 256 + threadIdx.x;
        if (i >= N_) return;
        int bi = batch[i];
        int bprev = (i == 0) ? -1 : batch[i - 1];
        for (int g = bprev + 1; g <= bi; ++g) gstart[g] = i;
        if (i == N_ - 1)
            for (int g = bi + 1; g <= NG; ++g) gstart[g] = N_;
    }
}

// ---------------------------------------------------------------------------
// Scan phase 1: block-local exclusive scan + block totals.
__global__ void scan_local_kernel(const int* __restrict__ deg, int* __restrict__ rs_part,
                                  int* __restrict__ blksum, int N_) {
    __shared__ int tmp[256];
    int t = threadIdx.x;
    int i = blockIdx.x * 256 + t;
    int v = (i < N_) ? deg[i] : 0;
    tmp[t] = v;
    __syncthreads();
    for (int off = 1; off < 256; off <<= 1) {
        int add = (t >= off) ? tmp[t - off] : 0;
        __syncthreads();
        tmp[t] += add;
        __syncthreads();
    }
    if (i < N_) rs_part[i] = tmp[t] - v;
    if (t == 255) blksum[blockIdx.x] = tmp[255];
}

// Scan phase 2: each block redundantly reduces blksum[0..b) (nblk<=256) in LDS,
// then writes rs/cursor for its 256 nodes. No single-block bottleneck.
__global__ void scan_final_kernel(const int* __restrict__ rs_part,
                                  const int* __restrict__ blksum,
                                  int* __restrict__ rs, int* __restrict__ cursor,
                                  int N_, int E_, int nblk) {
    __shared__ int tmp[256];
    int t = threadIdx.x;
    int b = blockIdx.x;
    tmp[t] = (t < b && t < nblk) ? blksum[t] : 0;   // only predecessors
    __syncthreads();
    for (int off = 128; off > 0; off >>= 1) {
        if (t < off) tmp[t] += tmp[t + off];
        __syncthreads();
    }
    int off0 = tmp[0];
    int i = b * 256 + t;
    if (i < N_) {
        int v = rs_part[i] + off0;
        rs[i] = v;
        cursor[i] = v;
    }
    if (i == 0) rs[N_] = E_;
}

// ---------------------------------------------------------------------------
// Fused: scatter (blocks [0, sblk)) + GEMM1 (blocks [sblk, sblk+gemmblk)).
// These are independent: scatter finalizes the CSR, gemm1 reads only x/W.
__global__ void scatter_gemm1_kernel(const int* __restrict__ ei, int* __restrict__ cursor,
                                     int* __restrict__ csr_src, int E_,
                                     const float* __restrict__ x,
                                     const float* __restrict__ Wl,
                                     const float* __restrict__ Wr,
                                     float* __restrict__ xl, float* __restrict__ xr,
                                     int N_, int sblk) {
    __shared__ float xs[8 * 64];
    int b = blockIdx.x;
    if (b < sblk) {
        int e = b * 256 + threadIdx.x;
        if (e < E_) {
            int d = ei[E_ + e];
            int pos = atomicAdd(&cursor[d], 1);
            csr_src[pos] = ei[e];
        }
        return;
    }
    // ---- GEMM1 path (round-8 kernel, verbatim) ----
    int r0 = (b - sblk) * 8;
    int t = threadIdx.x;
    for (int i = t; i < 8 * 64; i += 256) {
        int r = i >> 6;
        xs[i] = (r0 + r < N_) ? x[(long)(r0 + r) * 64 + (i & 63)] : 0.f;
    }
    __syncthreads();
    const float* W = (t < 128) ? Wl : Wr;
    int col = t & 127;
    float acc[8] = {0.f, 0.f, 0.f, 0.f, 0.f, 0.f, 0.f, 0.f};
    for (int k = 0; k < 64; ++k) {
        float w = W[k * 128 + col];
#pragma unroll
        for (int r = 0; r < 8; ++r) acc[r] += xs[r * 64 + k] * w;
    }
    float* out = (t < 128) ? xl : xr;
#pragma unroll
    for (int r = 0; r < 8; ++r)
        if (r0 + r < N_) out[(long)(r0 + r) * 128 + col] = acc[r];
}

// ---------------------------------------------------------------------------
// GEMM2: h1 (N x 128) @ Wl2 (128 x 64) -> xl2, @ Wr2 -> xr2.  (round-8 version)
__global__ void gemm2_kernel(const float* __restrict__ h1,
                             const float* __restrict__ Wl,
                             const float* __restrict__ Wr,
                             float* __restrict__ xl, float* __restrict__ xr,
                             int N_) {
    __shared__ float hs[8 * 128];
    int r0 = blockIdx.x * 8;
    int t = threadIdx.x;
    for (int i = t; i < 8 * 128; i += 128) {
        int r = i >> 7;
        hs[i] = (r0 + r < N_) ? h1[(long)(r0 + r) * 128 + (i & 127)] : 0.f;
    }
    __syncthreads();
    const float* W = (t < 64) ? Wl : Wr;
    int col = t & 63;
    float acc[8] = {0.f, 0.f, 0.f, 0.f, 0.f, 0.f, 0.f, 0.f};
    for (int k = 0; k < 128; ++k) {
        float w = W[k * 64 + col];
#pragma unroll
        for (int r = 0; r < 8; ++r) acc[r] += hs[r * 128 + k] * w;
    }
    float* out = (t < 64) ? xl : xr;
#pragma unroll
    for (int r = 0; r < 8; ++r)
        if (r0 + r < N_) out[(long)(r0 + r) * 64 + col] = acc[r];
}

// ---------------------------------------------------------------------------
// Fused GATv2 layer 1, HEAD-MERGED (round-9/10 version, verified).
__global__ void gat1_kernel(const float* __restrict__ xl,
                            float* __restrict__ xr,   // in: xr1, out: h1
                            const float* __restrict__ att,
                            const float* __restrict__ b1,
                            const int* __restrict__ rs,
                            const int* __restrict__ csr_src,
                            int N_) {
    int d = (int)(((long)blockIdx.x * blockDim.x + threadIdx.x) >> 6);
    int lane = threadIdx.x & 63;
    if (d >= N_) return;
    int slot = lane >> 5;     // 0..1
    int c8 = lane & 31;       // channel group: channels c8*4..+3 of 128
    long rowoff = (long)d * 128 + c8 * 4;
    const float4 xr4 = *(const float4*)(xr + rowoff);
    const float4 at4 = *(const float4*)(att + c8 * 4);

    int k0 = rs[d], k1 = rs[d + 1];
    int cnt = k1 - k0 + 1;    // virtual edges incl. self (slot 0)

    float4 acc = make_float4(0.f, 0.f, 0.f, 0.f);
    float den = 0.f;
    for (int c0 = 0; c0 < cnt; c0 += 64) {
        int wl = c0 + lane;
        int myidx = (wl >= 1 && wl < cnt) ? csr_src[k0 + wl - 1] : d;
        int lim = min(64, cnt - c0);
        for (int p = 0; p < lim; p += 4) {
            int e0 = p + slot, e1 = p + 2 + slot;
            int s0 = __shfl(myidx, e0, 64);
            int s1 = __shfl(myidx, e1, 64);
            bool v0 = e0 < lim, v1 = e1 < lim;
            float4 a0 = *(const float4*)(xl + (long)s0 * 128 + c8 * 4);
            float4 a1 = *(const float4*)(xl + (long)s1 * 128 + c8 * 4);
            float t, p0, p1;
            t = a0.x + xr4.x; t = fmaxf(t, 0.2f * t); p0  = at4.x * t;
            t = a0.y + xr4.y; t = fmaxf(t, 0.2f * t); p0 += at4.y * t;
            t = a0.z + xr4.z; t = fmaxf(t, 0.2f * t); p0 += at4.z * t;
            t = a0.w + xr4.w; t = fmaxf(t, 0.2f * t); p0 += at4.w * t;
            t = a1.x + xr4.x; t = fmaxf(t, 0.2f * t); p1  = at4.x * t;
            t = a1.y + xr4.y; t = fmaxf(t, 0.2f * t); p1 += at4.y * t;
            t = a1.z + xr4.z; t = fmaxf(t, 0.2f * t); p1 += at4.z * t;
            t = a1.w + xr4.w; t = fmaxf(t, 0.2f * t); p1 += at4.w * t;
            p0 += __shfl_xor(p0, 1, 64);  p1 += __shfl_xor(p1, 1, 64);
            p0 += __shfl_xor(p0, 2, 64);  p1 += __shfl_xor(p1, 2, 64);
            p0 += __shfl_xor(p0, 4, 64);  p1 += __shfl_xor(p1, 4, 64);
            p0 += __shfl_xor(p0, 8, 64);  p1 += __shfl_xor(p1, 8, 64);
            float w0 = v0 ? __expf(p0) : 0.f;
            float w1 = v1 ? __expf(p1) : 0.f;
            acc.x += w0 * a0.x + w1 * a1.x;
            acc.y += w0 * a0.y + w1 * a1.y;
            acc.z += w0 * a0.z + w1 * a1.z;
            acc.w += w0 * a0.w + w1 * a1.w;
            den += w0 + w1;
        }
    }
    acc.x += __shfl_xor(acc.x, 32, 64);
    acc.y += __shfl_xor(acc.y, 32, 64);
    acc.z += __shfl_xor(acc.z, 32, 64);
    acc.w += __shfl_xor(acc.w, 32, 64);
    den   += __shfl_xor(den, 32, 64);
    if (slot == 0) {
        const float4 b4 = *(const float4*)(b1 + c8 * 4);
        float inv = 1.f / den;
        float4 v;
        v.x = acc.x * inv + b4.x; v.x = (v.x > 0.f) ? v.x : __expf(v.x) - 1.f;
        v.y = acc.y * inv + b4.y; v.y = (v.y > 0.f) ? v.y : __expf(v.y) - 1.f;
        v.z = acc.z * inv + b4.z; v.z = (v.z > 0.f) ? v.z : __expf(v.z) - 1.f;
        v.w = acc.w * inv + b4.w; v.w = (v.w > 0.f) ? v.w : __expf(v.w) - 1.f;
        *(float4*)(xr + rowoff) = v;   // h1 in place
    }
}

// ---------------------------------------------------------------------------
// Fused GATv2 layer 2 (H=1, C=64): writes h2 row (no atomics).
__global__ void gat2_kernel(const float* __restrict__ xl,
                            const float* __restrict__ xr,
                            const float* __restrict__ att,
                            const float* __restrict__ b2,
                            const int* __restrict__ rs,
                            const int* __restrict__ csr_src,
                            float* __restrict__ h2,
                            int N_) {
    int d = (int)(((long)blockIdx.x * blockDim.x + threadIdx.x) >> 6);
    int lane = threadIdx.x & 63;
    if (d >= N_) return;
    int g = lane >> 4;
    int c4 = lane & 15;
    long rowoff = (long)d * 64 + c4 * 4;
    const float4 xr4 = *(const float4*)(xr + rowoff);
    const float4 at4 = *(const float4*)(att + c4 * 4);

    int k0 = rs[d], k1 = rs[d + 1];
    int cnt = k1 - k0 + 1;

    float4 acc = make_float4(0.f, 0.f, 0.f, 0.f);
    float den = 0.f;
    for (int c0 = 0; c0 < cnt; c0 += 64) {
        int wl = c0 + lane;
        int myidx = (wl >= 1 && wl < cnt) ? csr_src[k0 + wl - 1] : d;
        int lim = min(64, cnt - c0);
        for (int p = 0; p < lim; p += 8) {
            int e0 = p + g, e1 = p + 4 + g;
            int s0 = __shfl(myidx, e0, 64);
            int s1 = __shfl(myidx, e1, 64);
            bool v0 = e0 < lim, v1 = e1 < lim;
            float4 a0 = *(const float4*)(xl + (long)s0 * 64 + c4 * 4);
            float4 a1 = *(const float4*)(xl + (long)s1 * 64 + c4 * 4);
            float t, p0, p1;
            t = a0.x + xr4.x; t = fmaxf(t, 0.2f * t); p0  = at4.x * t;
            t = a0.y + xr4.y; t = fmaxf(t, 0.2f * t); p0 += at4.y * t;
            t = a0.z + xr4.z; t = fmaxf(t, 0.2f * t); p0 += at4.z * t;
            t = a0.w + xr4.w; t = fmaxf(t, 0.2f * t); p0 += at4.w * t;
            t = a1.x + xr4.x; t = fmaxf(t, 0.2f * t); p1  = at4.x * t;
            t = a1.y + xr4.y; t = fmaxf(t, 0.2f * t); p1 += at4.y * t;
            t = a1.z + xr4.z; t = fmaxf(t, 0.2f * t); p1 += at4.z * t;
            t = a1.w + xr4.w; t = fmaxf(t, 0.2f * t); p1 += at4.w * t;
            p0 += __shfl_xor(p0, 1, 64);  p1 += __shfl_xor(p1, 1, 64);
            p0 += __shfl_xor(p0, 2, 64);  p1 += __shfl_xor(p1, 2, 64);
            p0 += __shfl_xor(p0, 4, 64);  p1 += __shfl_xor(p1, 4, 64);
            p0 += __shfl_xor(p0, 8, 64);  p1 += __shfl_xor(p1, 8, 64);
            float w0 = v0 ? __expf(p0) : 0.f;
            float w1 = v1 ? __expf(p1) : 0.f;
            acc.x += w0 * a0.x + w1 * a1.x;
            acc.y += w0 * a0.y + w1 * a1.y;
            acc.z += w0 * a0.z + w1 * a1.z;
            acc.w += w0 * a0.w + w1 * a1.w;
            den += w0 + w1;
        }
    }
#pragma unroll
    for (int m = 16; m < 64; m <<= 1) {
        acc.x += __shfl_xor(acc.x, m, 64);
        acc.y += __shfl_xor(acc.y, m, 64);
        acc.z += __shfl_xor(acc.z, m, 64);
        acc.w += __shfl_xor(acc.w, m, 64);
        den   += __shfl_xor(den, m, 64);
    }
    if (g == 0) {
        const float4 b4 = *(const float4*)(b2 + c4 * 4);
        float inv = 1.f / den;
        float4 v;
        v.x = acc.x * inv + b4.x;
        v.y = acc.y * inv + b4.y;
        v.z = acc.z * inv + b4.z;
        v.w = acc.w * inv + b4.w;
        *(float4*)(h2 + rowoff) = v;
    }
}

// ---------------------------------------------------------------------------
// Segmented mean-pool over sorted batch ranges + 64x10 classifier.
__global__ void pool_final_kernel(const float* __restrict__ h2,
                                  const int* __restrict__ gstart,
                                  const float* __restrict__ lin_w,
                                  const float* __restrict__ lin_b,
                                  float* __restrict__ out) {
    int g = blockIdx.x;
    int lane = threadIdx.x;
    int s = gstart[g], e = gstart[g + 1];
    float acc = 0.f;
    int i = s;
    for (; i + 3 < e; i += 4) {
        float v0 = h2[(long)i * 64 + lane];
        float v1 = h2[(long)(i + 1) * 64 + lane];
        float v2 = h2[(long)(i + 2) * 64 + lane];
        float v3 = h2[(long)(i + 3) * 64 + lane];
        acc += (v0 + v1) + (v2 + v3);
    }
    for (; i < e; ++i) acc += h2[(long)i * 64 + lane];
    float pc = acc / fmaxf((float)(e - s), 1.f);
    __shared__ float pl[64];
    pl[lane] = pc;
    __syncthreads();
    if (lane < NCLS) {
        float o = lin_b[lane];
#pragma unroll 8
        for (int c = 0; c < 64; ++c) o += pl[c] * lin_w[c * NCLS + lane];
        out[g * NCLS + lane] = o;
    }
}

// ---------------------------------------------------------------------------
extern "C" void kernel_launch(void* const* d_in, const int* in_sizes, int n_in,
                              void* d_out, int out_size, void* d_ws, size_t ws_size,
                              hipStream_t stream) {
    const float* x     = (const float*)d_in[0];
    const int*   ei    = (const int*)d_in[1];
    const int*   batch = (const int*)d_in[2];
    const float* Wl1   = (const float*)d_in[3];
    const float* Wr1   = (const float*)d_in[4];
    const float* att1  = (const float*)d_in[5];
    const float* b1    = (const float*)d_in[6];
    const float* Wl2   = (const float*)d_in[7];
    const float* Wr2   = (const float*)d_in[8];
    const float* att2  = (const float*)d_in[9];
    const float* b2    = (const float*)d_in[10];
    const float* lin_w = (const float*)d_in[11];
    const float* lin_b = (const float*)d_in[12];
    float* out = (float*)d_out;

    const int N_ = in_sizes[0] / F_IN;   // 50000
    const int E_ = in_sizes[1] / 2;      // 800000

    // Workspace layout
    float* ws = (float*)d_ws;
    float* A = ws;                        // xl1 (N x 128); later xl2|xr2
    float* B = A + (long)N_ * 128;        // xr1 -> h1 in place; later h2 (N x 64)
    int* deg     = (int*)(B + (long)N_ * 128);  // N
    int* rs      = deg + N_;              // N+1
    int* cursor  = rs + N_ + 1;           // N
    int* csr_src = cursor + N_;           // E
    int* gstart  = csr_src + E_;          // NG+1
    int* rs_part = gstart + NG + 1;       // N
    int* blksum  = rs_part + N_;          // 256
    float* xl2 = A;
    float* xr2 = A + (long)N_ * 64;
    float* h2  = B;

    const int nblk = (N_ + 255) / 256;   // 196 for N=50000 (must be <= 256)
    const int cblk = (E_ + 255) / 256;   // 3125 count/scatter blocks
    const int gemmblk = (N_ + 7) / 8;    // 6250 gemm1 blocks

    // D1: zero degree counters
    hipMemsetAsync(deg, 0, (size_t)N_ * sizeof(int), stream);
    // D2: count edges + graph bounds (independent jobs, one launch)
    count_gbound_kernel<<<cblk + nblk, 256, 0, stream>>>(ei, deg, batch, gstart,
                                                         E_, N_, cblk);
    // D3: block-local scan
    scan_local_kernel<<<nblk, 256, 0, stream>>>(deg, rs_part, blksum, N_);
    // D4: finalize rs/cursor (each block redundantly reduces <=256 blksums)
    scan_final_kernel<<<nblk, 256, 0, stream>>>(rs_part, blksum, rs, cursor, N_, E_, nblk);
    // D5: scatter (CSR fill) || GEMM1 — independent, co-scheduled in one grid
    scatter_gemm1_kernel<<<cblk + gemmblk, 256, 0, stream>>>(
        ei, cursor, csr_src, E_, x, Wl1, Wr1, A, B, N_, cblk);
    // D6: GAT layer 1 (head-merged), h1 in place over B
    {
        int blocks = (int)(((long)N_ * 64 + 255) / 256);
        gat1_kernel<<<blocks, 256, 0, stream>>>(A, B, att1, b1, rs, csr_src, N_);
    }
    // D7: GEMM2
    gemm2_kernel<<<(N_ + 7) / 8, 128, 0, stream>>>(B, Wl2, Wr2, xl2, xr2, N_);
    // D8: GAT layer 2
    {
        int blocks = (int)(((long)N_ * 64 + 255) / 256);
        gat2_kernel<<<blocks, 256, 0, stream>>>(xl2, xr2, att2, b2, rs, csr_src, h2, N_);
    }
    // D9: segmented mean-pool + classifier
    pool_final_kernel<<<NG, 64, 0, stream>>>(h2, gstart, lin_w, lin_b, out);
}

// Round 12
// 285.197 us; speedup vs baseline: 1.1211x; 1.0187x over previous
//
#include <hip/hip_runtime.h>
#include <hip/hip_bf16.h>

#define F_IN 64
#define HID 64
#define NCLS 10
#define NG 512

// ---------------------------------------------------------------------------
// Fused: count (blocks [0, cblk)) + gbound (blocks [cblk, cblk+gblk)).
// gbound is tiny (196 blocks) -> no interference with count's atomics.
__global__ void count_gbound_kernel(const int* __restrict__ ei, int* __restrict__ deg,
                                    const int* __restrict__ batch, int* __restrict__ gstart,
                                    int E_, int N_, int cblk) {
    int b = blockIdx.x;
    if (b < cblk) {
        int e = b * 256 + threadIdx.x;
        if (e < E_) atomicAdd(&deg[ei[E_ + e]], 1);
    } else {
        int i = (b - cblk) * 256 + threadIdx.x;
        if (i >= N_) return;
        int bi = batch[i];
        int bprev = (i == 0) ? -1 : batch[i - 1];
        for (int g = bprev + 1; g <= bi; ++g) gstart[g] = i;
        if (i == N_ - 1)
            for (int g = bi + 1; g <= NG; ++g) gstart[g] = N_;
    }
}

// ---------------------------------------------------------------------------
// Scan phase 1: block-local exclusive scan + block totals.
__global__ void scan_local_kernel(const int* __restrict__ deg, int* __restrict__ rs_part,
                                  int* __restrict__ blksum, int N_) {
    __shared__ int tmp[256];
    int t = threadIdx.x;
    int i = blockIdx.x * 256 + t;
    int v = (i < N_) ? deg[i] : 0;
    tmp[t] = v;
    __syncthreads();
    for (int off = 1; off < 256; off <<= 1) {
        int add = (t >= off) ? tmp[t - off] : 0;
        __syncthreads();
        tmp[t] += add;
        __syncthreads();
    }
    if (i < N_) rs_part[i] = tmp[t] - v;
    if (t == 255) blksum[blockIdx.x] = tmp[255];
}

// Scan phase 2: each block redundantly reduces blksum[0..b) (nblk<=256) in LDS,
// then writes rs/cursor for its 256 nodes.
__global__ void scan_final_kernel(const int* __restrict__ rs_part,
                                  const int* __restrict__ blksum,
                                  int* __restrict__ rs, int* __restrict__ cursor,
                                  int N_, int E_, int nblk) {
    __shared__ int tmp[256];
    int t = threadIdx.x;
    int b = blockIdx.x;
    tmp[t] = (t < b && t < nblk) ? blksum[t] : 0;   // only predecessors
    __syncthreads();
    for (int off = 128; off > 0; off >>= 1) {
        if (t < off) tmp[t] += tmp[t + off];
        __syncthreads();
    }
    int off0 = tmp[0];
    int i = b * 256 + t;
    if (i < N_) {
        int v = rs_part[i] + off0;
        rs[i] = v;
        cursor[i] = v;
    }
    if (i == 0) rs[N_] = E_;
}

// ---------------------------------------------------------------------------
// Scatter: CSR fill (separate dispatch — fusing with gemm1 regressed, R11).
__global__ void scatter_kernel(const int* __restrict__ ei, int* __restrict__ cursor,
                               int* __restrict__ csr_src, int E_) {
    int e = blockIdx.x * 256 + threadIdx.x;
    if (e < E_) {
        int d = ei[E_ + e];
        int pos = atomicAdd(&cursor[d], 1);
        csr_src[pos] = ei[e];
    }
}

// ---------------------------------------------------------------------------
// GEMM1: x (N x 64) @ Wl1 (64 x 128) -> xl1, @ Wr1 -> xr1.  (round-8 version)
__global__ void gemm1_kernel(const float* __restrict__ x,
                             const float* __restrict__ Wl,
                             const float* __restrict__ Wr,
                             float* __restrict__ xl, float* __restrict__ xr,
                             int N_) {
    __shared__ float xs[8 * 64];
    int r0 = blockIdx.x * 8;
    int t = threadIdx.x;
    for (int i = t; i < 8 * 64; i += 256) {
        int r = i >> 6;
        xs[i] = (r0 + r < N_) ? x[(long)(r0 + r) * 64 + (i & 63)] : 0.f;
    }
    __syncthreads();
    const float* W = (t < 128) ? Wl : Wr;
    int col = t & 127;
    float acc[8] = {0.f, 0.f, 0.f, 0.f, 0.f, 0.f, 0.f, 0.f};
    for (int k = 0; k < 64; ++k) {
        float w = W[k * 128 + col];
#pragma unroll
        for (int r = 0; r < 8; ++r) acc[r] += xs[r * 64 + k] * w;
    }
    float* out = (t < 128) ? xl : xr;
#pragma unroll
    for (int r = 0; r < 8; ++r)
        if (r0 + r < N_) out[(long)(r0 + r) * 128 + col] = acc[r];
}

// ---------------------------------------------------------------------------
// GEMM2: h1 (N x 128) @ Wl2 (128 x 64) -> xl2, @ Wr2 -> xr2.  (round-8 version)
__global__ void gemm2_kernel(const float* __restrict__ h1,
                             const float* __restrict__ Wl,
                             const float* __restrict__ Wr,
                             float* __restrict__ xl, float* __restrict__ xr,
                             int N_) {
    __shared__ float hs[8 * 128];
    int r0 = blockIdx.x * 8;
    int t = threadIdx.x;
    for (int i = t; i < 8 * 128; i += 128) {
        int r = i >> 7;
        hs[i] = (r0 + r < N_) ? h1[(long)(r0 + r) * 128 + (i & 127)] : 0.f;
    }
    __syncthreads();
    const float* W = (t < 64) ? Wl : Wr;
    int col = t & 63;
    float acc[8] = {0.f, 0.f, 0.f, 0.f, 0.f, 0.f, 0.f, 0.f};
    for (int k = 0; k < 128; ++k) {
        float w = W[k * 64 + col];
#pragma unroll
        for (int r = 0; r < 8; ++r) acc[r] += hs[r * 128 + k] * w;
    }
    float* out = (t < 64) ? xl : xr;
#pragma unroll
    for (int r = 0; r < 8; ++r)
        if (r0 + r < N_) out[(long)(r0 + r) * 64 + col] = acc[r];
}

// ---------------------------------------------------------------------------
// Fused GATv2 layer 1, HEAD-MERGED (round-9/10 version, verified).
__global__ void gat1_kernel(const float* __restrict__ xl,
                            float* __restrict__ xr,   // in: xr1, out: h1
                            const float* __restrict__ att,
                            const float* __restrict__ b1,
                            const int* __restrict__ rs,
                            const int* __restrict__ csr_src,
                            int N_) {
    int d = (int)(((long)blockIdx.x * blockDim.x + threadIdx.x) >> 6);
    int lane = threadIdx.x & 63;
    if (d >= N_) return;
    int slot = lane >> 5;     // 0..1
    int c8 = lane & 31;       // channel group: channels c8*4..+3 of 128
    long rowoff = (long)d * 128 + c8 * 4;
    const float4 xr4 = *(const float4*)(xr + rowoff);
    const float4 at4 = *(const float4*)(att + c8 * 4);

    int k0 = rs[d], k1 = rs[d + 1];
    int cnt = k1 - k0 + 1;    // virtual edges incl. self (slot 0)

    float4 acc = make_float4(0.f, 0.f, 0.f, 0.f);
    float den = 0.f;
    for (int c0 = 0; c0 < cnt; c0 += 64) {
        int wl = c0 + lane;
        int myidx = (wl >= 1 && wl < cnt) ? csr_src[k0 + wl - 1] : d;
        int lim = min(64, cnt - c0);
        for (int p = 0; p < lim; p += 4) {
            int e0 = p + slot, e1 = p + 2 + slot;
            int s0 = __shfl(myidx, e0, 64);
            int s1 = __shfl(myidx, e1, 64);
            bool v0 = e0 < lim, v1 = e1 < lim;
            float4 a0 = *(const float4*)(xl + (long)s0 * 128 + c8 * 4);
            float4 a1 = *(const float4*)(xl + (long)s1 * 128 + c8 * 4);
            float t, p0, p1;
            t = a0.x + xr4.x; t = fmaxf(t, 0.2f * t); p0  = at4.x * t;
            t = a0.y + xr4.y; t = fmaxf(t, 0.2f * t); p0 += at4.y * t;
            t = a0.z + xr4.z; t = fmaxf(t, 0.2f * t); p0 += at4.z * t;
            t = a0.w + xr4.w; t = fmaxf(t, 0.2f * t); p0 += at4.w * t;
            t = a1.x + xr4.x; t = fmaxf(t, 0.2f * t); p1  = at4.x * t;
            t = a1.y + xr4.y; t = fmaxf(t, 0.2f * t); p1 += at4.y * t;
            t = a1.z + xr4.z; t = fmaxf(t, 0.2f * t); p1 += at4.z * t;
            t = a1.w + xr4.w; t = fmaxf(t, 0.2f * t); p1 += at4.w * t;
            p0 += __shfl_xor(p0, 1, 64);  p1 += __shfl_xor(p1, 1, 64);
            p0 += __shfl_xor(p0, 2, 64);  p1 += __shfl_xor(p1, 2, 64);
            p0 += __shfl_xor(p0, 4, 64);  p1 += __shfl_xor(p1, 4, 64);
            p0 += __shfl_xor(p0, 8, 64);  p1 += __shfl_xor(p1, 8, 64);
            float w0 = v0 ? __expf(p0) : 0.f;
            float w1 = v1 ? __expf(p1) : 0.f;
            acc.x += w0 * a0.x + w1 * a1.x;
            acc.y += w0 * a0.y + w1 * a1.y;
            acc.z += w0 * a0.z + w1 * a1.z;
            acc.w += w0 * a0.w + w1 * a1.w;
            den += w0 + w1;
        }
    }
    acc.x += __shfl_xor(acc.x, 32, 64);
    acc.y += __shfl_xor(acc.y, 32, 64);
    acc.z += __shfl_xor(acc.z, 32, 64);
    acc.w += __shfl_xor(acc.w, 32, 64);
    den   += __shfl_xor(den, 32, 64);
    if (slot == 0) {
        const float4 b4 = *(const float4*)(b1 + c8 * 4);
        float inv = 1.f / den;
        float4 v;
        v.x = acc.x * inv + b4.x; v.x = (v.x > 0.f) ? v.x : __expf(v.x) - 1.f;
        v.y = acc.y * inv + b4.y; v.y = (v.y > 0.f) ? v.y : __expf(v.y) - 1.f;
        v.z = acc.z * inv + b4.z; v.z = (v.z > 0.f) ? v.z : __expf(v.z) - 1.f;
        v.w = acc.w * inv + b4.w; v.w = (v.w > 0.f) ? v.w : __expf(v.w) - 1.f;
        *(float4*)(xr + rowoff) = v;   // h1 in place
    }
}

// ---------------------------------------------------------------------------
// Fused GATv2 layer 2 (H=1, C=64): writes h2 row (no atomics).
__global__ void gat2_kernel(const float* __restrict__ xl,
                            const float* __restrict__ xr,
                            const float* __restrict__ att,
                            const float* __restrict__ b2,
                            const int* __restrict__ rs,
                            const int* __restrict__ csr_src,
                            float* __restrict__ h2,
                            int N_) {
    int d = (int)(((long)blockIdx.x * blockDim.x + threadIdx.x) >> 6);
    int lane = threadIdx.x & 63;
    if (d >= N_) return;
    int g = lane >> 4;
    int c4 = lane & 15;
    long rowoff = (long)d * 64 + c4 * 4;
    const float4 xr4 = *(const float4*)(xr + rowoff);
    const float4 at4 = *(const float4*)(att + c4 * 4);

    int k0 = rs[d], k1 = rs[d + 1];
    int cnt = k1 - k0 + 1;

    float4 acc = make_float4(0.f, 0.f, 0.f, 0.f);
    float den = 0.f;
    for (int c0 = 0; c0 < cnt; c0 += 64) {
        int wl = c0 + lane;
        int myidx = (wl >= 1 && wl < cnt) ? csr_src[k0 + wl - 1] : d;
        int lim = min(64, cnt - c0);
        for (int p = 0; p < lim; p += 8) {
            int e0 = p + g, e1 = p + 4 + g;
            int s0 = __shfl(myidx, e0, 64);
            int s1 = __shfl(myidx, e1, 64);
            bool v0 = e0 < lim, v1 = e1 < lim;
            float4 a0 = *(const float4*)(xl + (long)s0 * 64 + c4 * 4);
            float4 a1 = *(const float4*)(xl + (long)s1 * 64 + c4 * 4);
            float t, p0, p1;
            t = a0.x + xr4.x; t = fmaxf(t, 0.2f * t); p0  = at4.x * t;
            t = a0.y + xr4.y; t = fmaxf(t, 0.2f * t); p0 += at4.y * t;
            t = a0.z + xr4.z; t = fmaxf(t, 0.2f * t); p0 += at4.z * t;
            t = a0.w + xr4.w; t = fmaxf(t, 0.2f * t); p0 += at4.w * t;
            t = a1.x + xr4.x; t = fmaxf(t, 0.2f * t); p1  = at4.x * t;
            t = a1.y + xr4.y; t = fmaxf(t, 0.2f * t); p1 += at4.y * t;
            t = a1.z + xr4.z; t = fmaxf(t, 0.2f * t); p1 += at4.z * t;
            t = a1.w + xr4.w; t = fmaxf(t, 0.2f * t); p1 += at4.w * t;
            p0 += __shfl_xor(p0, 1, 64);  p1 += __shfl_xor(p1, 1, 64);
            p0 += __shfl_xor(p0, 2, 64);  p1 += __shfl_xor(p1, 2, 64);
            p0 += __shfl_xor(p0, 4, 64);  p1 += __shfl_xor(p1, 4, 64);
            p0 += __shfl_xor(p0, 8, 64);  p1 += __shfl_xor(p1, 8, 64);
            float w0 = v0 ? __expf(p0) : 0.f;
            float w1 = v1 ? __expf(p1) : 0.f;
            acc.x += w0 * a0.x + w1 * a1.x;
            acc.y += w0 * a0.y + w1 * a1.y;
            acc.z += w0 * a0.z + w1 * a1.z;
            acc.w += w0 * a0.w + w1 * a1.w;
            den += w0 + w1;
        }
    }
#pragma unroll
    for (int m = 16; m < 64; m <<= 1) {
        acc.x += __shfl_xor(acc.x, m, 64);
        acc.y += __shfl_xor(acc.y, m, 64);
        acc.z += __shfl_xor(acc.z, m, 64);
        acc.w += __shfl_xor(acc.w, m, 64);
        den   += __shfl_xor(den, m, 64);
    }
    if (g == 0) {
        const float4 b4 = *(const float4*)(b2 + c4 * 4);
        float inv = 1.f / den;
        float4 v;
        v.x = acc.x * inv + b4.x;
        v.y = acc.y * inv + b4.y;
        v.z = acc.z * inv + b4.z;
        v.w = acc.w * inv + b4.w;
        *(float4*)(h2 + rowoff) = v;
    }
}

// ---------------------------------------------------------------------------
// Segmented mean-pool over sorted batch ranges + 64x10 classifier.
__global__ void pool_final_kernel(const float* __restrict__ h2,
                                  const int* __restrict__ gstart,
                                  const float* __restrict__ lin_w,
                                  const float* __restrict__ lin_b,
                                  float* __restrict__ out) {
    int g = blockIdx.x;
    int lane = threadIdx.x;
    int s = gstart[g], e = gstart[g + 1];
    float acc = 0.f;
    int i = s;
    for (; i + 3 < e; i += 4) {
        float v0 = h2[(long)i * 64 + lane];
        float v1 = h2[(long)(i + 1) * 64 + lane];
        float v2 = h2[(long)(i + 2) * 64 + lane];
        float v3 = h2[(long)(i + 3) * 64 + lane];
        acc += (v0 + v1) + (v2 + v3);
    }
    for (; i < e; ++i) acc += h2[(long)i * 64 + lane];
    float pc = acc / fmaxf((float)(e - s), 1.f);
    __shared__ float pl[64];
    pl[lane] = pc;
    __syncthreads();
    if (lane < NCLS) {
        float o = lin_b[lane];
#pragma unroll 8
        for (int c = 0; c < 64; ++c) o += pl[c] * lin_w[c * NCLS + lane];
        out[g * NCLS + lane] = o;
    }
}

// ---------------------------------------------------------------------------
extern "C" void kernel_launch(void* const* d_in, const int* in_sizes, int n_in,
                              void* d_out, int out_size, void* d_ws, size_t ws_size,
                              hipStream_t stream) {
    const float* x     = (const float*)d_in[0];
    const int*   ei    = (const int*)d_in[1];
    const int*   batch = (const int*)d_in[2];
    const float* Wl1   = (const float*)d_in[3];
    const float* Wr1   = (const float*)d_in[4];
    const float* att1  = (const float*)d_in[5];
    const float* b1    = (const float*)d_in[6];
    const float* Wl2   = (const float*)d_in[7];
    const float* Wr2   = (const float*)d_in[8];
    const float* att2  = (const float*)d_in[9];
    const float* b2    = (const float*)d_in[10];
    const float* lin_w = (const float*)d_in[11];
    const float* lin_b = (const float*)d_in[12];
    float* out = (float*)d_out;

    const int N_ = in_sizes[0] / F_IN;   // 50000
    const int E_ = in_sizes[1] / 2;      // 800000

    // Workspace layout
    float* ws = (float*)d_ws;
    float* A = ws;                        // xl1 (N x 128); later xl2|xr2
    float* B = A + (long)N_ * 128;        // xr1 -> h1 in place; later h2 (N x 64)
    int* deg     = (int*)(B + (long)N_ * 128);  // N
    int* rs      = deg + N_;              // N+1
    int* cursor  = rs + N_ + 1;           // N
    int* csr_src = cursor + N_;           // E
    int* gstart  = csr_src + E_;          // NG+1
    int* rs_part = gstart + NG + 1;       // N
    int* blksum  = rs_part + N_;          // 256
    float* xl2 = A;
    float* xr2 = A + (long)N_ * 64;
    float* h2  = B;

    const int nblk = (N_ + 255) / 256;   // 196 for N=50000 (must be <= 256)
    const int cblk = (E_ + 255) / 256;   // 3125 count/scatter blocks

    // D1: zero degree counters
    hipMemsetAsync(deg, 0, (size_t)N_ * sizeof(int), stream);
    // D2: count edges + graph bounds (tiny gbound piggybacks; no interference)
    count_gbound_kernel<<<cblk + nblk, 256, 0, stream>>>(ei, deg, batch, gstart,
                                                         E_, N_, cblk);
    // D3: block-local scan
    scan_local_kernel<<<nblk, 256, 0, stream>>>(deg, rs_part, blksum, N_);
    // D4: finalize rs/cursor
    scan_final_kernel<<<nblk, 256, 0, stream>>>(rs_part, blksum, rs, cursor, N_, E_, nblk);
    // D5: scatter (CSR fill) — separate: fusing with gemm1 regressed (R11)
    scatter_kernel<<<cblk, 256, 0, stream>>>(ei, cursor, csr_src, E_);
    // D6: GEMM1
    gemm1_kernel<<<(N_ + 7) / 8, 256, 0, stream>>>(x, Wl1, Wr1, A, B, N_);
    // D7: GAT layer 1 (head-merged), h1 in place over B
    {
        int blocks = (int)(((long)N_ * 64 + 255) / 256);
        gat1_kernel<<<blocks, 256, 0, stream>>>(A, B, att1, b1, rs, csr_src, N_);
    }
    // D8: GEMM2
    gemm2_kernel<<<(N_ + 7) / 8, 128, 0, stream>>>(B, Wl2, Wr2, xl2, xr2, N_);
    // D9: GAT layer 2
    {
        int blocks = (int)(((long)N_ * 64 + 255) / 256);
        gat2_kernel<<<blocks, 256, 0, stream>>>(xl2, xr2, att2, b2, rs, csr_src, h2, N_);
    }
    // D10: segmented mean-pool + classifier
    pool_final_kernel<<<NG, 64, 0, stream>>>(h2, gstart, lin_w, lin_b, out);
}

// Round 13
// 271.961 us; speedup vs baseline: 1.1757x; 1.0487x over previous
//
#include <hip/hip_runtime.h>
#include <hip/hip_bf16.h>

#define F_IN 64
#define HID 64
#define NCLS 10
#define NG 512

// bf16 helpers (RNE pack, cheap unpack)
__device__ __forceinline__ unsigned short f2bf(float f) {
    unsigned int u = __float_as_uint(f);
    unsigned int r = (u + 0x7fffu + ((u >> 16) & 1u)) >> 16;
    return (unsigned short)r;
}
__device__ __forceinline__ float bf2f(unsigned short h) {
    return __uint_as_float(((unsigned int)h) << 16);
}

// ---------------------------------------------------------------------------
// Fused: count (blocks [0, cblk)) + gbound (blocks [cblk, cblk+gblk)).
__global__ void count_gbound_kernel(const int* __restrict__ ei, int* __restrict__ deg,
                                    const int* __restrict__ batch, int* __restrict__ gstart,
                                    int E_, int N_, int cblk) {
    int b = blockIdx.x;
    if (b < cblk) {
        int e = b * 256 + threadIdx.x;
        if (e < E_) atomicAdd(&deg[ei[E_ + e]], 1);
    } else {
        int i = (b - cblk) * 256 + threadIdx.x;
        if (i >= N_) return;
        int bi = batch[i];
        int bprev = (i == 0) ? -1 : batch[i - 1];
        for (int g = bprev + 1; g <= bi; ++g) gstart[g] = i;
        if (i == N_ - 1)
            for (int g = bi + 1; g <= NG; ++g) gstart[g] = N_;
    }
}

// ---------------------------------------------------------------------------
__global__ void scan_local_kernel(const int* __restrict__ deg, int* __restrict__ rs_part,
                                  int* __restrict__ blksum, int N_) {
    __shared__ int tmp[256];
    int t = threadIdx.x;
    int i = blockIdx.x * 256 + t;
    int v = (i < N_) ? deg[i] : 0;
    tmp[t] = v;
    __syncthreads();
    for (int off = 1; off < 256; off <<= 1) {
        int add = (t >= off) ? tmp[t - off] : 0;
        __syncthreads();
        tmp[t] += add;
        __syncthreads();
    }
    if (i < N_) rs_part[i] = tmp[t] - v;
    if (t == 255) blksum[blockIdx.x] = tmp[255];
}

__global__ void scan_final_kernel(const int* __restrict__ rs_part,
                                  const int* __restrict__ blksum,
                                  int* __restrict__ rs, int* __restrict__ cursor,
                                  int N_, int E_, int nblk) {
    __shared__ int tmp[256];
    int t = threadIdx.x;
    int b = blockIdx.x;
    tmp[t] = (t < b && t < nblk) ? blksum[t] : 0;
    __syncthreads();
    for (int off = 128; off > 0; off >>= 1) {
        if (t < off) tmp[t] += tmp[t + off];
        __syncthreads();
    }
    int off0 = tmp[0];
    int i = b * 256 + t;
    if (i < N_) {
        int v = rs_part[i] + off0;
        rs[i] = v;
        cursor[i] = v;
    }
    if (i == 0) rs[N_] = E_;
}

// ---------------------------------------------------------------------------
__global__ void scatter_kernel(const int* __restrict__ ei, int* __restrict__ cursor,
                               int* __restrict__ csr_src, int E_) {
    int e = blockIdx.x * 256 + threadIdx.x;
    if (e < E_) {
        int d = ei[E_ + e];
        int pos = atomicAdd(&cursor[d], 1);
        csr_src[pos] = ei[e];
    }
}

// ---------------------------------------------------------------------------
// GEMM1: x @ Wl1 -> xl1 (bf16 gather table), @ Wr1 -> xr1 (fp32).
__global__ void gemm1_kernel(const float* __restrict__ x,
                             const float* __restrict__ Wl,
                             const float* __restrict__ Wr,
                             unsigned short* __restrict__ xlb,
                             float* __restrict__ xr,
                             int N_) {
    __shared__ float xs[8 * 64];
    int r0 = blockIdx.x * 8;
    int t = threadIdx.x;
    for (int i = t; i < 8 * 64; i += 256) {
        int r = i >> 6;
        xs[i] = (r0 + r < N_) ? x[(long)(r0 + r) * 64 + (i & 63)] : 0.f;
    }
    __syncthreads();
    const float* W = (t < 128) ? Wl : Wr;
    int col = t & 127;
    float acc[8] = {0.f, 0.f, 0.f, 0.f, 0.f, 0.f, 0.f, 0.f};
    for (int k = 0; k < 64; ++k) {
        float w = W[k * 128 + col];
#pragma unroll
        for (int r = 0; r < 8; ++r) acc[r] += xs[r * 64 + k] * w;
    }
    if (t < 128) {
#pragma unroll
        for (int r = 0; r < 8; ++r)
            if (r0 + r < N_) xlb[(long)(r0 + r) * 128 + col] = f2bf(acc[r]);
    } else {
#pragma unroll
        for (int r = 0; r < 8; ++r)
            if (r0 + r < N_) xr[(long)(r0 + r) * 128 + col] = acc[r];
    }
}

// ---------------------------------------------------------------------------
// GEMM2: h1 @ Wl2 -> xl2 (bf16 gather table), @ Wr2 -> xr2 (fp32).
__global__ void gemm2_kernel(const float* __restrict__ h1,
                             const float* __restrict__ Wl,
                             const float* __restrict__ Wr,
                             unsigned short* __restrict__ xlb,
                             float* __restrict__ xr,
                             int N_) {
    __shared__ float hs[8 * 128];
    int r0 = blockIdx.x * 8;
    int t = threadIdx.x;
    for (int i = t; i < 8 * 128; i += 128) {
        int r = i >> 7;
        hs[i] = (r0 + r < N_) ? h1[(long)(r0 + r) * 128 + (i & 127)] : 0.f;
    }
    __syncthreads();
    const float* W = (t < 64) ? Wl : Wr;
    int col = t & 63;
    float acc[8] = {0.f, 0.f, 0.f, 0.f, 0.f, 0.f, 0.f, 0.f};
    for (int k = 0; k < 128; ++k) {
        float w = W[k * 64 + col];
#pragma unroll
        for (int r = 0; r < 8; ++r) acc[r] += hs[r * 128 + k] * w;
    }
    if (t < 64) {
#pragma unroll
        for (int r = 0; r < 8; ++r)
            if (r0 + r < N_) xlb[(long)(r0 + r) * 64 + col] = f2bf(acc[r]);
    } else {
#pragma unroll
        for (int r = 0; r < 8; ++r)
            if (r0 + r < N_) xr[(long)(r0 + r) * 64 + col] = acc[r];
    }
}

// ---------------------------------------------------------------------------
// Fused GATv2 layer 1, HEAD-MERGED, bf16 xl gather table.
__global__ void gat1_kernel(const unsigned short* __restrict__ xlb,
                            float* __restrict__ xr,   // in: xr1, out: h1
                            const float* __restrict__ att,
                            const float* __restrict__ b1,
                            const int* __restrict__ rs,
                            const int* __restrict__ csr_src,
                            int N_) {
    int d = (int)(((long)blockIdx.x * blockDim.x + threadIdx.x) >> 6);
    int lane = threadIdx.x & 63;
    if (d >= N_) return;
    int slot = lane >> 5;     // 0..1
    int c8 = lane & 31;       // channel group: channels c8*4..+3 of 128
    long rowoff = (long)d * 128 + c8 * 4;
    const float4 xr4 = *(const float4*)(xr + rowoff);
    const float4 at4 = *(const float4*)(att + c8 * 4);

    int k0 = rs[d], k1 = rs[d + 1];
    int cnt = k1 - k0 + 1;

    float4 acc = make_float4(0.f, 0.f, 0.f, 0.f);
    float den = 0.f;
    for (int c0 = 0; c0 < cnt; c0 += 64) {
        int wl = c0 + lane;
        int myidx = (wl >= 1 && wl < cnt) ? csr_src[k0 + wl - 1] : d;
        int lim = min(64, cnt - c0);
        for (int p = 0; p < lim; p += 4) {
            int e0 = p + slot, e1 = p + 2 + slot;
            int s0 = __shfl(myidx, e0, 64);
            int s1 = __shfl(myidx, e1, 64);
            bool v0 = e0 < lim, v1 = e1 < lim;
            ushort4 u0 = *(const ushort4*)(xlb + (long)s0 * 128 + c8 * 4);
            ushort4 u1 = *(const ushort4*)(xlb + (long)s1 * 128 + c8 * 4);
            float4 a0 = make_float4(bf2f(u0.x), bf2f(u0.y), bf2f(u0.z), bf2f(u0.w));
            float4 a1 = make_float4(bf2f(u1.x), bf2f(u1.y), bf2f(u1.z), bf2f(u1.w));
            float t, p0, p1;
            t = a0.x + xr4.x; t = fmaxf(t, 0.2f * t); p0  = at4.x * t;
            t = a0.y + xr4.y; t = fmaxf(t, 0.2f * t); p0 += at4.y * t;
            t = a0.z + xr4.z; t = fmaxf(t, 0.2f * t); p0 += at4.z * t;
            t = a0.w + xr4.w; t = fmaxf(t, 0.2f * t); p0 += at4.w * t;
            t = a1.x + xr4.x; t = fmaxf(t, 0.2f * t); p1  = at4.x * t;
            t = a1.y + xr4.y; t = fmaxf(t, 0.2f * t); p1 += at4.y * t;
            t = a1.z + xr4.z; t = fmaxf(t, 0.2f * t); p1 += at4.z * t;
            t = a1.w + xr4.w; t = fmaxf(t, 0.2f * t); p1 += at4.w * t;
            p0 += __shfl_xor(p0, 1, 64);  p1 += __shfl_xor(p1, 1, 64);
            p0 += __shfl_xor(p0, 2, 64);  p1 += __shfl_xor(p1, 2, 64);
            p0 += __shfl_xor(p0, 4, 64);  p1 += __shfl_xor(p1, 4, 64);
            p0 += __shfl_xor(p0, 8, 64);  p1 += __shfl_xor(p1, 8, 64);
            float w0 = v0 ? __expf(p0) : 0.f;
            float w1 = v1 ? __expf(p1) : 0.f;
            acc.x += w0 * a0.x + w1 * a1.x;
            acc.y += w0 * a0.y + w1 * a1.y;
            acc.z += w0 * a0.z + w1 * a1.z;
            acc.w += w0 * a0.w + w1 * a1.w;
            den += w0 + w1;
        }
    }
    acc.x += __shfl_xor(acc.x, 32, 64);
    acc.y += __shfl_xor(acc.y, 32, 64);
    acc.z += __shfl_xor(acc.z, 32, 64);
    acc.w += __shfl_xor(acc.w, 32, 64);
    den   += __shfl_xor(den, 32, 64);
    if (slot == 0) {
        const float4 b4 = *(const float4*)(b1 + c8 * 4);
        float inv = 1.f / den;
        float4 v;
        v.x = acc.x * inv + b4.x; v.x = (v.x > 0.f) ? v.x : __expf(v.x) - 1.f;
        v.y = acc.y * inv + b4.y; v.y = (v.y > 0.f) ? v.y : __expf(v.y) - 1.f;
        v.z = acc.z * inv + b4.z; v.z = (v.z > 0.f) ? v.z : __expf(v.z) - 1.f;
        v.w = acc.w * inv + b4.w; v.w = (v.w > 0.f) ? v.w : __expf(v.w) - 1.f;
        *(float4*)(xr + rowoff) = v;   // h1 in place
    }
}

// ---------------------------------------------------------------------------
// Fused GATv2 layer 2, bf16 xl gather table; writes h2 fp32.
__global__ void gat2_kernel(const unsigned short* __restrict__ xlb,
                            const float* __restrict__ xr,
                            const float* __restrict__ att,
                            const float* __restrict__ b2,
                            const int* __restrict__ rs,
                            const int* __restrict__ csr_src,
                            float* __restrict__ h2,
                            int N_) {
    int d = (int)(((long)blockIdx.x * blockDim.x + threadIdx.x) >> 6);
    int lane = threadIdx.x & 63;
    if (d >= N_) return;
    int g = lane >> 4;
    int c4 = lane & 15;
    long rowoff = (long)d * 64 + c4 * 4;
    const float4 xr4 = *(const float4*)(xr + rowoff);
    const float4 at4 = *(const float4*)(att + c4 * 4);

    int k0 = rs[d], k1 = rs[d + 1];
    int cnt = k1 - k0 + 1;

    float4 acc = make_float4(0.f, 0.f, 0.f, 0.f);
    float den = 0.f;
    for (int c0 = 0; c0 < cnt; c0 += 64) {
        int wl = c0 + lane;
        int myidx = (wl >= 1 && wl < cnt) ? csr_src[k0 + wl - 1] : d;
        int lim = min(64, cnt - c0);
        for (int p = 0; p < lim; p += 8) {
            int e0 = p + g, e1 = p + 4 + g;
            int s0 = __shfl(myidx, e0, 64);
            int s1 = __shfl(myidx, e1, 64);
            bool v0 = e0 < lim, v1 = e1 < lim;
            ushort4 u0 = *(const ushort4*)(xlb + (long)s0 * 64 + c4 * 4);
            ushort4 u1 = *(const ushort4*)(xlb + (long)s1 * 64 + c4 * 4);
            float4 a0 = make_float4(bf2f(u0.x), bf2f(u0.y), bf2f(u0.z), bf2f(u0.w));
            float4 a1 = make_float4(bf2f(u1.x), bf2f(u1.y), bf2f(u1.z), bf2f(u1.w));
            float t, p0, p1;
            t = a0.x + xr4.x; t = fmaxf(t, 0.2f * t); p0  = at4.x * t;
            t = a0.y + xr4.y; t = fmaxf(t, 0.2f * t); p0 += at4.y * t;
            t = a0.z + xr4.z; t = fmaxf(t, 0.2f * t); p0 += at4.z * t;
            t = a0.w + xr4.w; t = fmaxf(t, 0.2f * t); p0 += at4.w * t;
            t = a1.x + xr4.x; t = fmaxf(t, 0.2f * t); p1  = at4.x * t;
            t = a1.y + xr4.y; t = fmaxf(t, 0.2f * t); p1 += at4.y * t;
            t = a1.z + xr4.z; t = fmaxf(t, 0.2f * t); p1 += at4.z * t;
            t = a1.w + xr4.w; t = fmaxf(t, 0.2f * t); p1 += at4.w * t;
            p0 += __shfl_xor(p0, 1, 64);  p1 += __shfl_xor(p1, 1, 64);
            p0 += __shfl_xor(p0, 2, 64);  p1 += __shfl_xor(p1, 2, 64);
            p0 += __shfl_xor(p0, 4, 64);  p1 += __shfl_xor(p1, 4, 64);
            p0 += __shfl_xor(p0, 8, 64);  p1 += __shfl_xor(p1, 8, 64);
            float w0 = v0 ? __expf(p0) : 0.f;
            float w1 = v1 ? __expf(p1) : 0.f;
            acc.x += w0 * a0.x + w1 * a1.x;
            acc.y += w0 * a0.y + w1 * a1.y;
            acc.z += w0 * a0.z + w1 * a1.z;
            acc.w += w0 * a0.w + w1 * a1.w;
            den += w0 + w1;
        }
    }
#pragma unroll
    for (int m = 16; m < 64; m <<= 1) {
        acc.x += __shfl_xor(acc.x, m, 64);
        acc.y += __shfl_xor(acc.y, m, 64);
        acc.z += __shfl_xor(acc.z, m, 64);
        acc.w += __shfl_xor(acc.w, m, 64);
        den   += __shfl_xor(den, m, 64);
    }
    if (g == 0) {
        const float4 b4 = *(const float4*)(b2 + c4 * 4);
        float inv = 1.f / den;
        float4 v;
        v.x = acc.x * inv + b4.x;
        v.y = acc.y * inv + b4.y;
        v.z = acc.z * inv + b4.z;
        v.w = acc.w * inv + b4.w;
        *(float4*)(h2 + rowoff) = v;
    }
}

// ---------------------------------------------------------------------------
// Segmented mean-pool over sorted batch ranges + 64x10 classifier.
__global__ void pool_final_kernel(const float* __restrict__ h2,
                                  const int* __restrict__ gstart,
                                  const float* __restrict__ lin_w,
                                  const float* __restrict__ lin_b,
                                  float* __restrict__ out) {
    int g = blockIdx.x;
    int lane = threadIdx.x;
    int s = gstart[g], e = gstart[g + 1];
    float acc = 0.f;
    int i = s;
    for (; i + 3 < e; i += 4) {
        float v0 = h2[(long)i * 64 + lane];
        float v1 = h2[(long)(i + 1) * 64 + lane];
        float v2 = h2[(long)(i + 2) * 64 + lane];
        float v3 = h2[(long)(i + 3) * 64 + lane];
        acc += (v0 + v1) + (v2 + v3);
    }
    for (; i < e; ++i) acc += h2[(long)i * 64 + lane];
    float pc = acc / fmaxf((float)(e - s), 1.f);
    __shared__ float pl[64];
    pl[lane] = pc;
    __syncthreads();
    if (lane < NCLS) {
        float o = lin_b[lane];
#pragma unroll 8
        for (int c = 0; c < 64; ++c) o += pl[c] * lin_w[c * NCLS + lane];
        out[g * NCLS + lane] = o;
    }
}

// ---------------------------------------------------------------------------
extern "C" void kernel_launch(void* const* d_in, const int* in_sizes, int n_in,
                              void* d_out, int out_size, void* d_ws, size_t ws_size,
                              hipStream_t stream) {
    const float* x     = (const float*)d_in[0];
    const int*   ei    = (const int*)d_in[1];
    const int*   batch = (const int*)d_in[2];
    const float* Wl1   = (const float*)d_in[3];
    const float* Wr1   = (const float*)d_in[4];
    const float* att1  = (const float*)d_in[5];
    const float* b1    = (const float*)d_in[6];
    const float* Wl2   = (const float*)d_in[7];
    const float* Wr2   = (const float*)d_in[8];
    const float* att2  = (const float*)d_in[9];
    const float* b2    = (const float*)d_in[10];
    const float* lin_w = (const float*)d_in[11];
    const float* lin_b = (const float*)d_in[12];
    float* out = (float*)d_out;

    const int N_ = in_sizes[0] / F_IN;   // 50000
    const int E_ = in_sizes[1] / 2;      // 800000

    // Workspace layout
    float* ws = (float*)d_ws;
    float* B = ws;                                        // xr1 -> h1 in place (N x 128); h2 reuses first N x 64
    unsigned short* xl1b = (unsigned short*)(B + (long)N_ * 128);   // N x 128 bf16
    unsigned short* xl2b = xl1b + (long)N_ * 128;                   // N x 64 bf16
    float* xr2 = (float*)(xl2b + (long)N_ * 64);          // N x 64 fp32
    int* deg     = (int*)(xr2 + (long)N_ * 64);           // N
    int* rs      = deg + N_;                              // N+1
    int* cursor  = rs + N_ + 1;                           // N
    int* csr_src = cursor + N_;                           // E
    int* gstart  = csr_src + E_;                          // NG+1
    int* rs_part = gstart + NG + 1;                       // N
    int* blksum  = rs_part + N_;                          // 256
    float* h2 = B;

    const int nblk = (N_ + 255) / 256;   // 196 (must be <= 256)
    const int cblk = (E_ + 255) / 256;   // 3125

    // D1: zero degree counters
    hipMemsetAsync(deg, 0, (size_t)N_ * sizeof(int), stream);
    // D2: count edges + graph bounds
    count_gbound_kernel<<<cblk + nblk, 256, 0, stream>>>(ei, deg, batch, gstart,
                                                         E_, N_, cblk);
    // D3/D4: device-wide scan
    scan_local_kernel<<<nblk, 256, 0, stream>>>(deg, rs_part, blksum, N_);
    scan_final_kernel<<<nblk, 256, 0, stream>>>(rs_part, blksum, rs, cursor, N_, E_, nblk);
    // D5: scatter (CSR fill)
    scatter_kernel<<<cblk, 256, 0, stream>>>(ei, cursor, csr_src, E_);
    // D6: GEMM1 -> xl1 (bf16), xr1 (fp32)
    gemm1_kernel<<<(N_ + 7) / 8, 256, 0, stream>>>(x, Wl1, Wr1, xl1b, B, N_);
    // D7: GAT layer 1 (head-merged, bf16 gathers), h1 in place over B
    {
        int blocks = (int)(((long)N_ * 64 + 255) / 256);
        gat1_kernel<<<blocks, 256, 0, stream>>>(xl1b, B, att1, b1, rs, csr_src, N_);
    }
    // D8: GEMM2 -> xl2 (bf16), xr2 (fp32)
    gemm2_kernel<<<(N_ + 7) / 8, 128, 0, stream>>>(B, Wl2, Wr2, xl2b, xr2, N_);
    // D9: GAT layer 2 (bf16 gathers) -> h2
    {
        int blocks = (int)(((long)N_ * 64 + 255) / 256);
        gat2_kernel<<<blocks, 256, 0, stream>>>(xl2b, xr2, att2, b2, rs, csr_src, h2, N_);
    }
    // D10: segmented mean-pool + classifier
    pool_final_kernel<<<NG, 64, 0, stream>>>(h2, gstart, lin_w, lin_b, out);
}

// Round 14
// 253.935 us; speedup vs baseline: 1.2591x; 1.0710x over previous
//
#include <hip/hip_runtime.h>
#include <hip/hip_bf16.h>

#define F_IN 64
#define HID 64
#define NCLS 10
#define NG 512

// bf16 helpers (RNE pack, cheap unpack)
__device__ __forceinline__ unsigned short f2bf(float f) {
    unsigned int u = __float_as_uint(f);
    unsigned int r = (u + 0x7fffu + ((u >> 16) & 1u)) >> 16;
    return (unsigned short)r;
}
__device__ __forceinline__ float bf2f(unsigned short h) {
    return __uint_as_float(((unsigned int)h) << 16);
}

// ---------------------------------------------------------------------------
// Fused: XCD-sharded count (blocks [0, 8*csh)) + gbound (blocks after).
// Shard k (= blockIdx&7, matching MI355X's round-robin block->XCD map) only
// processes edges with dst in node-slice k -> deg writes confined to one
// XCD's L2 slice, lines fully combined before writeback.
__global__ void count_gbound_kernel(const int* __restrict__ ei, int* __restrict__ deg,
                                    const int* __restrict__ batch, int* __restrict__ gstart,
                                    int E_, int N_, int csh) {
    int b = blockIdx.x;
    if (b < csh * 8) {
        int shard = b & 7;
        int chunk = b >> 3;
        int slice = (N_ + 7) >> 3;
        int lo = shard * slice, hi = min(N_, lo + slice);
        int stride = csh * 256;
        for (int e = chunk * 256 + threadIdx.x; e < E_; e += stride) {
            int d = ei[E_ + e];
            if (d >= lo && d < hi) atomicAdd(&deg[d], 1);
        }
    } else {
        int i = (b - csh * 8) * 256 + threadIdx.x;
        if (i >= N_) return;
        int bi = batch[i];
        int bprev = (i == 0) ? -1 : batch[i - 1];
        for (int g = bprev + 1; g <= bi; ++g) gstart[g] = i;
        if (i == N_ - 1)
            for (int g = bi + 1; g <= NG; ++g) gstart[g] = N_;
    }
}

// ---------------------------------------------------------------------------
__global__ void scan_local_kernel(const int* __restrict__ deg, int* __restrict__ rs_part,
                                  int* __restrict__ blksum, int N_) {
    __shared__ int tmp[256];
    int t = threadIdx.x;
    int i = blockIdx.x * 256 + t;
    int v = (i < N_) ? deg[i] : 0;
    tmp[t] = v;
    __syncthreads();
    for (int off = 1; off < 256; off <<= 1) {
        int add = (t >= off) ? tmp[t - off] : 0;
        __syncthreads();
        tmp[t] += add;
        __syncthreads();
    }
    if (i < N_) rs_part[i] = tmp[t] - v;
    if (t == 255) blksum[blockIdx.x] = tmp[255];
}

__global__ void scan_final_kernel(const int* __restrict__ rs_part,
                                  const int* __restrict__ blksum,
                                  int* __restrict__ rs, int* __restrict__ cursor,
                                  int N_, int E_, int nblk) {
    __shared__ int tmp[256];
    int t = threadIdx.x;
    int b = blockIdx.x;
    tmp[t] = (t < b && t < nblk) ? blksum[t] : 0;
    __syncthreads();
    for (int off = 128; off > 0; off >>= 1) {
        if (t < off) tmp[t] += tmp[t + off];
        __syncthreads();
    }
    int off0 = tmp[0];
    int i = b * 256 + t;
    if (i < N_) {
        int v = rs_part[i] + off0;
        rs[i] = v;
        cursor[i] = v;
    }
    if (i == 0) rs[N_] = E_;
}

// ---------------------------------------------------------------------------
// XCD-sharded scatter: shard k handles dst slice k; csr_src/cursor writes
// stay within one XCD's contiguous region -> L2 write-combining works.
__global__ void scatter_kernel(const int* __restrict__ ei, int* __restrict__ cursor,
                               int* __restrict__ csr_src, int E_, int N_, int csh) {
    int shard = blockIdx.x & 7;
    int chunk = blockIdx.x >> 3;
    int slice = (N_ + 7) >> 3;
    int lo = shard * slice, hi = min(N_, lo + slice);
    int stride = csh * 256;
    for (int e = chunk * 256 + threadIdx.x; e < E_; e += stride) {
        int d = ei[E_ + e];
        if (d >= lo && d < hi) {
            int pos = atomicAdd(&cursor[d], 1);
            csr_src[pos] = ei[e];
        }
    }
}

// ---------------------------------------------------------------------------
// GEMM1: x @ Wl1 -> xl1 (bf16 gather table), @ Wr1 -> xr1 (fp32).
__global__ void gemm1_kernel(const float* __restrict__ x,
                             const float* __restrict__ Wl,
                             const float* __restrict__ Wr,
                             unsigned short* __restrict__ xlb,
                             float* __restrict__ xr,
                             int N_) {
    __shared__ float xs[8 * 64];
    int r0 = blockIdx.x * 8;
    int t = threadIdx.x;
    for (int i = t; i < 8 * 64; i += 256) {
        int r = i >> 6;
        xs[i] = (r0 + r < N_) ? x[(long)(r0 + r) * 64 + (i & 63)] : 0.f;
    }
    __syncthreads();
    const float* W = (t < 128) ? Wl : Wr;
    int col = t & 127;
    float acc[8] = {0.f, 0.f, 0.f, 0.f, 0.f, 0.f, 0.f, 0.f};
    for (int k = 0; k < 64; ++k) {
        float w = W[k * 128 + col];
#pragma unroll
        for (int r = 0; r < 8; ++r) acc[r] += xs[r * 64 + k] * w;
    }
    if (t < 128) {
#pragma unroll
        for (int r = 0; r < 8; ++r)
            if (r0 + r < N_) xlb[(long)(r0 + r) * 128 + col] = f2bf(acc[r]);
    } else {
#pragma unroll
        for (int r = 0; r < 8; ++r)
            if (r0 + r < N_) xr[(long)(r0 + r) * 128 + col] = acc[r];
    }
}

// ---------------------------------------------------------------------------
// GEMM2: h1 @ Wl2 -> xl2 (bf16 gather table), @ Wr2 -> xr2 (fp32).
__global__ void gemm2_kernel(const float* __restrict__ h1,
                             const float* __restrict__ Wl,
                             const float* __restrict__ Wr,
                             unsigned short* __restrict__ xlb,
                             float* __restrict__ xr,
                             int N_) {
    __shared__ float hs[8 * 128];
    int r0 = blockIdx.x * 8;
    int t = threadIdx.x;
    for (int i = t; i < 8 * 128; i += 128) {
        int r = i >> 7;
        hs[i] = (r0 + r < N_) ? h1[(long)(r0 + r) * 128 + (i & 127)] : 0.f;
    }
    __syncthreads();
    const float* W = (t < 64) ? Wl : Wr;
    int col = t & 63;
    float acc[8] = {0.f, 0.f, 0.f, 0.f, 0.f, 0.f, 0.f, 0.f};
    for (int k = 0; k < 128; ++k) {
        float w = W[k * 64 + col];
#pragma unroll
        for (int r = 0; r < 8; ++r) acc[r] += hs[r * 128 + k] * w;
    }
    if (t < 64) {
#pragma unroll
        for (int r = 0; r < 8; ++r)
            if (r0 + r < N_) xlb[(long)(r0 + r) * 64 + col] = f2bf(acc[r]);
    } else {
#pragma unroll
        for (int r = 0; r < 8; ++r)
            if (r0 + r < N_) xr[(long)(r0 + r) * 64 + col] = acc[r];
    }
}

// ---------------------------------------------------------------------------
// Fused GATv2 layer 1, HEAD-MERGED, bf16 xl gather table.
__global__ void gat1_kernel(const unsigned short* __restrict__ xlb,
                            float* __restrict__ xr,   // in: xr1, out: h1
                            const float* __restrict__ att,
                            const float* __restrict__ b1,
                            const int* __restrict__ rs,
                            const int* __restrict__ csr_src,
                            int N_) {
    int d = (int)(((long)blockIdx.x * blockDim.x + threadIdx.x) >> 6);
    int lane = threadIdx.x & 63;
    if (d >= N_) return;
    int slot = lane >> 5;     // 0..1
    int c8 = lane & 31;       // channel group: channels c8*4..+3 of 128
    long rowoff = (long)d * 128 + c8 * 4;
    const float4 xr4 = *(const float4*)(xr + rowoff);
    const float4 at4 = *(const float4*)(att + c8 * 4);

    int k0 = rs[d], k1 = rs[d + 1];
    int cnt = k1 - k0 + 1;

    float4 acc = make_float4(0.f, 0.f, 0.f, 0.f);
    float den = 0.f;
    for (int c0 = 0; c0 < cnt; c0 += 64) {
        int wl = c0 + lane;
        int myidx = (wl >= 1 && wl < cnt) ? csr_src[k0 + wl - 1] : d;
        int lim = min(64, cnt - c0);
        for (int p = 0; p < lim; p += 4) {
            int e0 = p + slot, e1 = p + 2 + slot;
            int s0 = __shfl(myidx, e0, 64);
            int s1 = __shfl(myidx, e1, 64);
            bool v0 = e0 < lim, v1 = e1 < lim;
            ushort4 u0 = *(const ushort4*)(xlb + (long)s0 * 128 + c8 * 4);
            ushort4 u1 = *(const ushort4*)(xlb + (long)s1 * 128 + c8 * 4);
            float4 a0 = make_float4(bf2f(u0.x), bf2f(u0.y), bf2f(u0.z), bf2f(u0.w));
            float4 a1 = make_float4(bf2f(u1.x), bf2f(u1.y), bf2f(u1.z), bf2f(u1.w));
            float t, p0, p1;
            t = a0.x + xr4.x; t = fmaxf(t, 0.2f * t); p0  = at4.x * t;
            t = a0.y + xr4.y; t = fmaxf(t, 0.2f * t); p0 += at4.y * t;
            t = a0.z + xr4.z; t = fmaxf(t, 0.2f * t); p0 += at4.z * t;
            t = a0.w + xr4.w; t = fmaxf(t, 0.2f * t); p0 += at4.w * t;
            t = a1.x + xr4.x; t = fmaxf(t, 0.2f * t); p1  = at4.x * t;
            t = a1.y + xr4.y; t = fmaxf(t, 0.2f * t); p1 += at4.y * t;
            t = a1.z + xr4.z; t = fmaxf(t, 0.2f * t); p1 += at4.z * t;
            t = a1.w + xr4.w; t = fmaxf(t, 0.2f * t); p1 += at4.w * t;
            p0 += __shfl_xor(p0, 1, 64);  p1 += __shfl_xor(p1, 1, 64);
            p0 += __shfl_xor(p0, 2, 64);  p1 += __shfl_xor(p1, 2, 64);
            p0 += __shfl_xor(p0, 4, 64);  p1 += __shfl_xor(p1, 4, 64);
            p0 += __shfl_xor(p0, 8, 64);  p1 += __shfl_xor(p1, 8, 64);
            float w0 = v0 ? __expf(p0) : 0.f;
            float w1 = v1 ? __expf(p1) : 0.f;
            acc.x += w0 * a0.x + w1 * a1.x;
            acc.y += w0 * a0.y + w1 * a1.y;
            acc.z += w0 * a0.z + w1 * a1.z;
            acc.w += w0 * a0.w + w1 * a1.w;
            den += w0 + w1;
        }
    }
    acc.x += __shfl_xor(acc.x, 32, 64);
    acc.y += __shfl_xor(acc.y, 32, 64);
    acc.z += __shfl_xor(acc.z, 32, 64);
    acc.w += __shfl_xor(acc.w, 32, 64);
    den   += __shfl_xor(den, 32, 64);
    if (slot == 0) {
        const float4 b4 = *(const float4*)(b1 + c8 * 4);
        float inv = 1.f / den;
        float4 v;
        v.x = acc.x * inv + b4.x; v.x = (v.x > 0.f) ? v.x : __expf(v.x) - 1.f;
        v.y = acc.y * inv + b4.y; v.y = (v.y > 0.f) ? v.y : __expf(v.y) - 1.f;
        v.z = acc.z * inv + b4.z; v.z = (v.z > 0.f) ? v.z : __expf(v.z) - 1.f;
        v.w = acc.w * inv + b4.w; v.w = (v.w > 0.f) ? v.w : __expf(v.w) - 1.f;
        *(float4*)(xr + rowoff) = v;   // h1 in place
    }
}

// ---------------------------------------------------------------------------
// Fused GATv2 layer 2, bf16 xl gather table; writes h2 fp32.
__global__ void gat2_kernel(const unsigned short* __restrict__ xlb,
                            const float* __restrict__ xr,
                            const float* __restrict__ att,
                            const float* __restrict__ b2,
                            const int* __restrict__ rs,
                            const int* __restrict__ csr_src,
                            float* __restrict__ h2,
                            int N_) {
    int d = (int)(((long)blockIdx.x * blockDim.x + threadIdx.x) >> 6);
    int lane = threadIdx.x & 63;
    if (d >= N_) return;
    int g = lane >> 4;
    int c4 = lane & 15;
    long rowoff = (long)d * 64 + c4 * 4;
    const float4 xr4 = *(const float4*)(xr + rowoff);
    const float4 at4 = *(const float4*)(att + c4 * 4);

    int k0 = rs[d], k1 = rs[d + 1];
    int cnt = k1 - k0 + 1;

    float4 acc = make_float4(0.f, 0.f, 0.f, 0.f);
    float den = 0.f;
    for (int c0 = 0; c0 < cnt; c0 += 64) {
        int wl = c0 + lane;
        int myidx = (wl >= 1 && wl < cnt) ? csr_src[k0 + wl - 1] : d;
        int lim = min(64, cnt - c0);
        for (int p = 0; p < lim; p += 8) {
            int e0 = p + g, e1 = p + 4 + g;
            int s0 = __shfl(myidx, e0, 64);
            int s1 = __shfl(myidx, e1, 64);
            bool v0 = e0 < lim, v1 = e1 < lim;
            ushort4 u0 = *(const ushort4*)(xlb + (long)s0 * 64 + c4 * 4);
            ushort4 u1 = *(const ushort4*)(xlb + (long)s1 * 64 + c4 * 4);
            float4 a0 = make_float4(bf2f(u0.x), bf2f(u0.y), bf2f(u0.z), bf2f(u0.w));
            float4 a1 = make_float4(bf2f(u1.x), bf2f(u1.y), bf2f(u1.z), bf2f(u1.w));
            float t, p0, p1;
            t = a0.x + xr4.x; t = fmaxf(t, 0.2f * t); p0  = at4.x * t;
            t = a0.y + xr4.y; t = fmaxf(t, 0.2f * t); p0 += at4.y * t;
            t = a0.z + xr4.z; t = fmaxf(t, 0.2f * t); p0 += at4.z * t;
            t = a0.w + xr4.w; t = fmaxf(t, 0.2f * t); p0 += at4.w * t;
            t = a1.x + xr4.x; t = fmaxf(t, 0.2f * t); p1  = at4.x * t;
            t = a1.y + xr4.y; t = fmaxf(t, 0.2f * t); p1 += at4.y * t;
            t = a1.z + xr4.z; t = fmaxf(t, 0.2f * t); p1 += at4.z * t;
            t = a1.w + xr4.w; t = fmaxf(t, 0.2f * t); p1 += at4.w * t;
            p0 += __shfl_xor(p0, 1, 64);  p1 += __shfl_xor(p1, 1, 64);
            p0 += __shfl_xor(p0, 2, 64);  p1 += __shfl_xor(p1, 2, 64);
            p0 += __shfl_xor(p0, 4, 64);  p1 += __shfl_xor(p1, 4, 64);
            p0 += __shfl_xor(p0, 8, 64);  p1 += __shfl_xor(p1, 8, 64);
            float w0 = v0 ? __expf(p0) : 0.f;
            float w1 = v1 ? __expf(p1) : 0.f;
            acc.x += w0 * a0.x + w1 * a1.x;
            acc.y += w0 * a0.y + w1 * a1.y;
            acc.z += w0 * a0.z + w1 * a1.z;
            acc.w += w0 * a0.w + w1 * a1.w;
            den += w0 + w1;
        }
    }
#pragma unroll
    for (int m = 16; m < 64; m <<= 1) {
        acc.x += __shfl_xor(acc.x, m, 64);
        acc.y += __shfl_xor(acc.y, m, 64);
        acc.z += __shfl_xor(acc.z, m, 64);
        acc.w += __shfl_xor(acc.w, m, 64);
        den   += __shfl_xor(den, m, 64);
    }
    if (g == 0) {
        const float4 b4 = *(const float4*)(b2 + c4 * 4);
        float inv = 1.f / den;
        float4 v;
        v.x = acc.x * inv + b4.x;
        v.y = acc.y * inv + b4.y;
        v.z = acc.z * inv + b4.z;
        v.w = acc.w * inv + b4.w;
        *(float4*)(h2 + rowoff) = v;
    }
}

// ---------------------------------------------------------------------------
// Segmented mean-pool over sorted batch ranges + 64x10 classifier.
__global__ void pool_final_kernel(const float* __restrict__ h2,
                                  const int* __restrict__ gstart,
                                  const float* __restrict__ lin_w,
                                  const float* __restrict__ lin_b,
                                  float* __restrict__ out) {
    int g = blockIdx.x;
    int lane = threadIdx.x;
    int s = gstart[g], e = gstart[g + 1];
    float acc = 0.f;
    int i = s;
    for (; i + 3 < e; i += 4) {
        float v0 = h2[(long)i * 64 + lane];
        float v1 = h2[(long)(i + 1) * 64 + lane];
        float v2 = h2[(long)(i + 2) * 64 + lane];
        float v3 = h2[(long)(i + 3) * 64 + lane];
        acc += (v0 + v1) + (v2 + v3);
    }
    for (; i < e; ++i) acc += h2[(long)i * 64 + lane];
    float pc = acc / fmaxf((float)(e - s), 1.f);
    __shared__ float pl[64];
    pl[lane] = pc;
    __syncthreads();
    if (lane < NCLS) {
        float o = lin_b[lane];
#pragma unroll 8
        for (int c = 0; c < 64; ++c) o += pl[c] * lin_w[c * NCLS + lane];
        out[g * NCLS + lane] = o;
    }
}

// ---------------------------------------------------------------------------
extern "C" void kernel_launch(void* const* d_in, const int* in_sizes, int n_in,
                              void* d_out, int out_size, void* d_ws, size_t ws_size,
                              hipStream_t stream) {
    const float* x     = (const float*)d_in[0];
    const int*   ei    = (const int*)d_in[1];
    const int*   batch = (const int*)d_in[2];
    const float* Wl1   = (const float*)d_in[3];
    const float* Wr1   = (const float*)d_in[4];
    const float* att1  = (const float*)d_in[5];
    const float* b1    = (const float*)d_in[6];
    const float* Wl2   = (const float*)d_in[7];
    const float* Wr2   = (const float*)d_in[8];
    const float* att2  = (const float*)d_in[9];
    const float* b2    = (const float*)d_in[10];
    const float* lin_w = (const float*)d_in[11];
    const float* lin_b = (const float*)d_in[12];
    float* out = (float*)d_out;

    const int N_ = in_sizes[0] / F_IN;   // 50000
    const int E_ = in_sizes[1] / 2;      // 800000

    // Workspace layout
    float* ws = (float*)d_ws;
    float* B = ws;                                        // xr1 -> h1 in place (N x 128); h2 reuses first N x 64
    unsigned short* xl1b = (unsigned short*)(B + (long)N_ * 128);   // N x 128 bf16
    unsigned short* xl2b = xl1b + (long)N_ * 128;                   // N x 64 bf16
    float* xr2 = (float*)(xl2b + (long)N_ * 64);          // N x 64 fp32
    int* deg     = (int*)(xr2 + (long)N_ * 64);           // N
    int* rs      = deg + N_;                              // N+1
    int* cursor  = rs + N_ + 1;                           // N
    int* csr_src = cursor + N_;                           // E
    int* gstart  = csr_src + E_;                          // NG+1
    int* rs_part = gstart + NG + 1;                       // N
    int* blksum  = rs_part + N_;                          // 256
    float* h2 = B;

    const int nblk = (N_ + 255) / 256;   // 196 (must be <= 256)
    const int csh  = 391;                // blocks per shard: 391*256*8 > E

    // D1: zero degree counters
    hipMemsetAsync(deg, 0, (size_t)N_ * sizeof(int), stream);
    // D2: XCD-sharded count + graph bounds
    count_gbound_kernel<<<csh * 8 + nblk, 256, 0, stream>>>(ei, deg, batch, gstart,
                                                            E_, N_, csh);
    // D3/D4: device-wide scan
    scan_local_kernel<<<nblk, 256, 0, stream>>>(deg, rs_part, blksum, N_);
    scan_final_kernel<<<nblk, 256, 0, stream>>>(rs_part, blksum, rs, cursor, N_, E_, nblk);
    // D5: XCD-sharded scatter (CSR fill)
    scatter_kernel<<<csh * 8, 256, 0, stream>>>(ei, cursor, csr_src, E_, N_, csh);
    // D6: GEMM1 -> xl1 (bf16), xr1 (fp32)
    gemm1_kernel<<<(N_ + 7) / 8, 256, 0, stream>>>(x, Wl1, Wr1, xl1b, B, N_);
    // D7: GAT layer 1 (head-merged, bf16 gathers), h1 in place over B
    {
        int blocks = (int)(((long)N_ * 64 + 255) / 256);
        gat1_kernel<<<blocks, 256, 0, stream>>>(xl1b, B, att1, b1, rs, csr_src, N_);
    }
    // D8: GEMM2 -> xl2 (bf16), xr2 (fp32)
    gemm2_kernel<<<(N_ + 7) / 8, 128, 0, stream>>>(B, Wl2, Wr2, xl2b, xr2, N_);
    // D9: GAT layer 2 (bf16 gathers) -> h2
    {
        int blocks = (int)(((long)N_ * 64 + 255) / 256);
        gat2_kernel<<<blocks, 256, 0, stream>>>(xl2b, xr2, att2, b2, rs, csr_src, h2, N_);
    }
    // D10: segmented mean-pool + classifier
    pool_final_kernel<<<NG, 64, 0, stream>>>(h2, gstart, lin_w, lin_b, out);
}

// Round 15
// 245.841 us; speedup vs baseline: 1.3006x; 1.0329x over previous
//
#include <hip/hip_runtime.h>
#include <hip/hip_bf16.h>

#define F_IN 64
#define HID 64
#define NCLS 10
#define NG 512

// bf16 helpers (RNE pack, cheap unpack)
__device__ __forceinline__ unsigned short f2bf(float f) {
    unsigned int u = __float_as_uint(f);
    unsigned int r = (u + 0x7fffu + ((u >> 16) & 1u)) >> 16;
    return (unsigned short)r;
}
__device__ __forceinline__ float bf2f(unsigned short h) {
    return __uint_as_float(((unsigned int)h) << 16);
}
__device__ __forceinline__ float4 bf4(ushort4 u) {
    return make_float4(bf2f(u.x), bf2f(u.y), bf2f(u.z), bf2f(u.w));
}

// ---------------------------------------------------------------------------
// Fused: XCD-sharded count + gbound.
__global__ void count_gbound_kernel(const int* __restrict__ ei, int* __restrict__ deg,
                                    const int* __restrict__ batch, int* __restrict__ gstart,
                                    int E_, int N_, int csh) {
    int b = blockIdx.x;
    if (b < csh * 8) {
        int shard = b & 7;
        int chunk = b >> 3;
        int slice = (N_ + 7) >> 3;
        int lo = shard * slice, hi = min(N_, lo + slice);
        int stride = csh * 256;
        for (int e = chunk * 256 + threadIdx.x; e < E_; e += stride) {
            int d = ei[E_ + e];
            if (d >= lo && d < hi) atomicAdd(&deg[d], 1);
        }
    } else {
        int i = (b - csh * 8) * 256 + threadIdx.x;
        if (i >= N_) return;
        int bi = batch[i];
        int bprev = (i == 0) ? -1 : batch[i - 1];
        for (int g = bprev + 1; g <= bi; ++g) gstart[g] = i;
        if (i == N_ - 1)
            for (int g = bi + 1; g <= NG; ++g) gstart[g] = N_;
    }
}

// ---------------------------------------------------------------------------
__global__ void scan_local_kernel(const int* __restrict__ deg, int* __restrict__ rs_part,
                                  int* __restrict__ blksum, int N_) {
    __shared__ int tmp[256];
    int t = threadIdx.x;
    int i = blockIdx.x * 256 + t;
    int v = (i < N_) ? deg[i] : 0;
    tmp[t] = v;
    __syncthreads();
    for (int off = 1; off < 256; off <<= 1) {
        int add = (t >= off) ? tmp[t - off] : 0;
        __syncthreads();
        tmp[t] += add;
        __syncthreads();
    }
    if (i < N_) rs_part[i] = tmp[t] - v;
    if (t == 255) blksum[blockIdx.x] = tmp[255];
}

__global__ void scan_final_kernel(const int* __restrict__ rs_part,
                                  const int* __restrict__ blksum,
                                  int* __restrict__ rs, int* __restrict__ cursor,
                                  int N_, int E_, int nblk) {
    __shared__ int tmp[256];
    int t = threadIdx.x;
    int b = blockIdx.x;
    tmp[t] = (t < b && t < nblk) ? blksum[t] : 0;
    __syncthreads();
    for (int off = 128; off > 0; off >>= 1) {
        if (t < off) tmp[t] += tmp[t + off];
        __syncthreads();
    }
    int off0 = tmp[0];
    int i = b * 256 + t;
    if (i < N_) {
        int v = rs_part[i] + off0;
        rs[i] = v;
        cursor[i] = v;
    }
    if (i == 0) rs[N_] = E_;
}

// ---------------------------------------------------------------------------
// XCD-sharded scatter.
__global__ void scatter_kernel(const int* __restrict__ ei, int* __restrict__ cursor,
                               int* __restrict__ csr_src, int E_, int N_, int csh) {
    int shard = blockIdx.x & 7;
    int chunk = blockIdx.x >> 3;
    int slice = (N_ + 7) >> 3;
    int lo = shard * slice, hi = min(N_, lo + slice);
    int stride = csh * 256;
    for (int e = chunk * 256 + threadIdx.x; e < E_; e += stride) {
        int d = ei[E_ + e];
        if (d >= lo && d < hi) {
            int pos = atomicAdd(&cursor[d], 1);
            csr_src[pos] = ei[e];
        }
    }
}

// ---------------------------------------------------------------------------
// GEMM1: x @ Wl1 -> xl1 (bf16), @ Wr1 -> xr1 (bf16).
__global__ void gemm1_kernel(const float* __restrict__ x,
                             const float* __restrict__ Wl,
                             const float* __restrict__ Wr,
                             unsigned short* __restrict__ xlb,
                             unsigned short* __restrict__ xrb,
                             int N_) {
    __shared__ float xs[8 * 64];
    int r0 = blockIdx.x * 8;
    int t = threadIdx.x;
    for (int i = t; i < 8 * 64; i += 256) {
        int r = i >> 6;
        xs[i] = (r0 + r < N_) ? x[(long)(r0 + r) * 64 + (i & 63)] : 0.f;
    }
    __syncthreads();
    const float* W = (t < 128) ? Wl : Wr;
    int col = t & 127;
    float acc[8] = {0.f, 0.f, 0.f, 0.f, 0.f, 0.f, 0.f, 0.f};
    for (int k = 0; k < 64; ++k) {
        float w = W[k * 128 + col];
#pragma unroll
        for (int r = 0; r < 8; ++r) acc[r] += xs[r * 64 + k] * w;
    }
    unsigned short* out = (t < 128) ? xlb : xrb;
#pragma unroll
    for (int r = 0; r < 8; ++r)
        if (r0 + r < N_) out[(long)(r0 + r) * 128 + col] = f2bf(acc[r]);
}

// ---------------------------------------------------------------------------
// GEMM2: h1 (bf16) @ Wl2 -> xl2 (bf16), @ Wr2 -> xr2 (bf16).
__global__ void gemm2_kernel(const unsigned short* __restrict__ h1,
                             const float* __restrict__ Wl,
                             const float* __restrict__ Wr,
                             unsigned short* __restrict__ xlb,
                             unsigned short* __restrict__ xrb,
                             int N_) {
    __shared__ float hs[8 * 128];
    int r0 = blockIdx.x * 8;
    int t = threadIdx.x;
    // 8 rows x 128 ch = 1024 bf16 = 256 ushort4
    for (int j = t; j < 256; j += 128) {
        int row = j >> 5, c4 = j & 31;
        float4 v = make_float4(0.f, 0.f, 0.f, 0.f);
        if (r0 + row < N_)
            v = bf4(*(const ushort4*)(h1 + (long)(r0 + row) * 128 + c4 * 4));
        *(float4*)(hs + row * 128 + c4 * 4) = v;
    }
    __syncthreads();
    const float* W = (t < 64) ? Wl : Wr;
    int col = t & 63;
    float acc[8] = {0.f, 0.f, 0.f, 0.f, 0.f, 0.f, 0.f, 0.f};
    for (int k = 0; k < 128; ++k) {
        float w = W[k * 64 + col];
#pragma unroll
        for (int r = 0; r < 8; ++r) acc[r] += hs[r * 128 + k] * w;
    }
    unsigned short* out = (t < 64) ? xlb : xrb;
#pragma unroll
    for (int r = 0; r < 8; ++r)
        if (r0 + r < N_) out[(long)(r0 + r) * 64 + col] = f2bf(acc[r]);
}

// ---------------------------------------------------------------------------
// Fused GATv2 layer 1, HEAD-MERGED, all-bf16 tensors (xl gather, xr in, h1 out).
__global__ void gat1_kernel(const unsigned short* __restrict__ xlb,
                            unsigned short* __restrict__ xrb,  // in: xr1, out: h1
                            const float* __restrict__ att,
                            const float* __restrict__ b1,
                            const int* __restrict__ rs,
                            const int* __restrict__ csr_src,
                            int N_) {
    int d = (int)(((long)blockIdx.x * blockDim.x + threadIdx.x) >> 6);
    int lane = threadIdx.x & 63;
    if (d >= N_) return;
    int slot = lane >> 5;     // 0..1
    int c8 = lane & 31;       // channel group: channels c8*4..+3 of 128
    long rowoff = (long)d * 128 + c8 * 4;
    const float4 xr4 = bf4(*(const ushort4*)(xrb + rowoff));
    const float4 at4 = *(const float4*)(att + c8 * 4);

    int k0 = rs[d], k1 = rs[d + 1];
    int cnt = k1 - k0 + 1;

    float4 acc = make_float4(0.f, 0.f, 0.f, 0.f);
    float den = 0.f;
    for (int c0 = 0; c0 < cnt; c0 += 64) {
        int wl = c0 + lane;
        int myidx = (wl >= 1 && wl < cnt) ? csr_src[k0 + wl - 1] : d;
        int lim = min(64, cnt - c0);
        for (int p = 0; p < lim; p += 4) {
            int e0 = p + slot, e1 = p + 2 + slot;
            int s0 = __shfl(myidx, e0, 64);
            int s1 = __shfl(myidx, e1, 64);
            bool v0 = e0 < lim, v1 = e1 < lim;
            float4 a0 = bf4(*(const ushort4*)(xlb + (long)s0 * 128 + c8 * 4));
            float4 a1 = bf4(*(const ushort4*)(xlb + (long)s1 * 128 + c8 * 4));
            float t, p0, p1;
            t = a0.x + xr4.x; t = fmaxf(t, 0.2f * t); p0  = at4.x * t;
            t = a0.y + xr4.y; t = fmaxf(t, 0.2f * t); p0 += at4.y * t;
            t = a0.z + xr4.z; t = fmaxf(t, 0.2f * t); p0 += at4.z * t;
            t = a0.w + xr4.w; t = fmaxf(t, 0.2f * t); p0 += at4.w * t;
            t = a1.x + xr4.x; t = fmaxf(t, 0.2f * t); p1  = at4.x * t;
            t = a1.y + xr4.y; t = fmaxf(t, 0.2f * t); p1 += at4.y * t;
            t = a1.z + xr4.z; t = fmaxf(t, 0.2f * t); p1 += at4.z * t;
            t = a1.w + xr4.w; t = fmaxf(t, 0.2f * t); p1 += at4.w * t;
            p0 += __shfl_xor(p0, 1, 64);  p1 += __shfl_xor(p1, 1, 64);
            p0 += __shfl_xor(p0, 2, 64);  p1 += __shfl_xor(p1, 2, 64);
            p0 += __shfl_xor(p0, 4, 64);  p1 += __shfl_xor(p1, 4, 64);
            p0 += __shfl_xor(p0, 8, 64);  p1 += __shfl_xor(p1, 8, 64);
            float w0 = v0 ? __expf(p0) : 0.f;
            float w1 = v1 ? __expf(p1) : 0.f;
            acc.x += w0 * a0.x + w1 * a1.x;
            acc.y += w0 * a0.y + w1 * a1.y;
            acc.z += w0 * a0.z + w1 * a1.z;
            acc.w += w0 * a0.w + w1 * a1.w;
            den += w0 + w1;
        }
    }
    acc.x += __shfl_xor(acc.x, 32, 64);
    acc.y += __shfl_xor(acc.y, 32, 64);
    acc.z += __shfl_xor(acc.z, 32, 64);
    acc.w += __shfl_xor(acc.w, 32, 64);
    den   += __shfl_xor(den, 32, 64);
    if (slot == 0) {
        const float4 b4 = *(const float4*)(b1 + c8 * 4);
        float inv = 1.f / den;
        float4 v;
        v.x = acc.x * inv + b4.x; v.x = (v.x > 0.f) ? v.x : __expf(v.x) - 1.f;
        v.y = acc.y * inv + b4.y; v.y = (v.y > 0.f) ? v.y : __expf(v.y) - 1.f;
        v.z = acc.z * inv + b4.z; v.z = (v.z > 0.f) ? v.z : __expf(v.z) - 1.f;
        v.w = acc.w * inv + b4.w; v.w = (v.w > 0.f) ? v.w : __expf(v.w) - 1.f;
        ushort4 o;
        o.x = f2bf(v.x); o.y = f2bf(v.y); o.z = f2bf(v.z); o.w = f2bf(v.w);
        *(ushort4*)(xrb + rowoff) = o;   // h1 in place (bf16)
    }
}

// ---------------------------------------------------------------------------
// Fused GATv2 layer 2, all-bf16 tensors; writes h2 bf16.
__global__ void gat2_kernel(const unsigned short* __restrict__ xlb,
                            const unsigned short* __restrict__ xrb,
                            const float* __restrict__ att,
                            const float* __restrict__ b2,
                            const int* __restrict__ rs,
                            const int* __restrict__ csr_src,
                            unsigned short* __restrict__ h2,
                            int N_) {
    int d = (int)(((long)blockIdx.x * blockDim.x + threadIdx.x) >> 6);
    int lane = threadIdx.x & 63;
    if (d >= N_) return;
    int g = lane >> 4;
    int c4 = lane & 15;
    long rowoff = (long)d * 64 + c4 * 4;
    const float4 xr4 = bf4(*(const ushort4*)(xrb + rowoff));
    const float4 at4 = *(const float4*)(att + c4 * 4);

    int k0 = rs[d], k1 = rs[d + 1];
    int cnt = k1 - k0 + 1;

    float4 acc = make_float4(0.f, 0.f, 0.f, 0.f);
    float den = 0.f;
    for (int c0 = 0; c0 < cnt; c0 += 64) {
        int wl = c0 + lane;
        int myidx = (wl >= 1 && wl < cnt) ? csr_src[k0 + wl - 1] : d;
        int lim = min(64, cnt - c0);
        for (int p = 0; p < lim; p += 8) {
            int e0 = p + g, e1 = p + 4 + g;
            int s0 = __shfl(myidx, e0, 64);
            int s1 = __shfl(myidx, e1, 64);
            bool v0 = e0 < lim, v1 = e1 < lim;
            float4 a0 = bf4(*(const ushort4*)(xlb + (long)s0 * 64 + c4 * 4));
            float4 a1 = bf4(*(const ushort4*)(xlb + (long)s1 * 64 + c4 * 4));
            float t, p0, p1;
            t = a0.x + xr4.x; t = fmaxf(t, 0.2f * t); p0  = at4.x * t;
            t = a0.y + xr4.y; t = fmaxf(t, 0.2f * t); p0 += at4.y * t;
            t = a0.z + xr4.z; t = fmaxf(t, 0.2f * t); p0 += at4.z * t;
            t = a0.w + xr4.w; t = fmaxf(t, 0.2f * t); p0 += at4.w * t;
            t = a1.x + xr4.x; t = fmaxf(t, 0.2f * t); p1  = at4.x * t;
            t = a1.y + xr4.y; t = fmaxf(t, 0.2f * t); p1 += at4.y * t;
            t = a1.z + xr4.z; t = fmaxf(t, 0.2f * t); p1 += at4.z * t;
            t = a1.w + xr4.w; t = fmaxf(t, 0.2f * t); p1 += at4.w * t;
            p0 += __shfl_xor(p0, 1, 64);  p1 += __shfl_xor(p1, 1, 64);
            p0 += __shfl_xor(p0, 2, 64);  p1 += __shfl_xor(p1, 2, 64);
            p0 += __shfl_xor(p0, 4, 64);  p1 += __shfl_xor(p1, 4, 64);
            p0 += __shfl_xor(p0, 8, 64);  p1 += __shfl_xor(p1, 8, 64);
            float w0 = v0 ? __expf(p0) : 0.f;
            float w1 = v1 ? __expf(p1) : 0.f;
            acc.x += w0 * a0.x + w1 * a1.x;
            acc.y += w0 * a0.y + w1 * a1.y;
            acc.z += w0 * a0.z + w1 * a1.z;
            acc.w += w0 * a0.w + w1 * a1.w;
            den += w0 + w1;
        }
    }
#pragma unroll
    for (int m = 16; m < 64; m <<= 1) {
        acc.x += __shfl_xor(acc.x, m, 64);
        acc.y += __shfl_xor(acc.y, m, 64);
        acc.z += __shfl_xor(acc.z, m, 64);
        acc.w += __shfl_xor(acc.w, m, 64);
        den   += __shfl_xor(den, m, 64);
    }
    if (g == 0) {
        const float4 b4 = *(const float4*)(b2 + c4 * 4);
        float inv = 1.f / den;
        ushort4 o;
        o.x = f2bf(acc.x * inv + b4.x);
        o.y = f2bf(acc.y * inv + b4.y);
        o.z = f2bf(acc.z * inv + b4.z);
        o.w = f2bf(acc.w * inv + b4.w);
        *(ushort4*)(h2 + rowoff) = o;
    }
}

// ---------------------------------------------------------------------------
// Segmented mean-pool (h2 bf16) + 64x10 classifier.
__global__ void pool_final_kernel(const unsigned short* __restrict__ h2,
                                  const int* __restrict__ gstart,
                                  const float* __restrict__ lin_w,
                                  const float* __restrict__ lin_b,
                                  float* __restrict__ out) {
    int g = blockIdx.x;
    int lane = threadIdx.x;
    int s = gstart[g], e = gstart[g + 1];
    float acc = 0.f;
    int i = s;
    for (; i + 3 < e; i += 4) {
        float v0 = bf2f(h2[(long)i * 64 + lane]);
        float v1 = bf2f(h2[(long)(i + 1) * 64 + lane]);
        float v2 = bf2f(h2[(long)(i + 2) * 64 + lane]);
        float v3 = bf2f(h2[(long)(i + 3) * 64 + lane]);
        acc += (v0 + v1) + (v2 + v3);
    }
    for (; i < e; ++i) acc += bf2f(h2[(long)i * 64 + lane]);
    float pc = acc / fmaxf((float)(e - s), 1.f);
    __shared__ float pl[64];
    pl[lane] = pc;
    __syncthreads();
    if (lane < NCLS) {
        float o = lin_b[lane];
#pragma unroll 8
        for (int c = 0; c < 64; ++c) o += pl[c] * lin_w[c * NCLS + lane];
        out[g * NCLS + lane] = o;
    }
}

// ---------------------------------------------------------------------------
extern "C" void kernel_launch(void* const* d_in, const int* in_sizes, int n_in,
                              void* d_out, int out_size, void* d_ws, size_t ws_size,
                              hipStream_t stream) {
    const float* x     = (const float*)d_in[0];
    const int*   ei    = (const int*)d_in[1];
    const int*   batch = (const int*)d_in[2];
    const float* Wl1   = (const float*)d_in[3];
    const float* Wr1   = (const float*)d_in[4];
    const float* att1  = (const float*)d_in[5];
    const float* b1    = (const float*)d_in[6];
    const float* Wl2   = (const float*)d_in[7];
    const float* Wr2   = (const float*)d_in[8];
    const float* att2  = (const float*)d_in[9];
    const float* b2    = (const float*)d_in[10];
    const float* lin_w = (const float*)d_in[11];
    const float* lin_b = (const float*)d_in[12];
    float* out = (float*)d_out;

    const int N_ = in_sizes[0] / F_IN;   // 50000
    const int E_ = in_sizes[1] / 2;      // 800000

    // Workspace layout (all intermediates bf16)
    unsigned short* B    = (unsigned short*)d_ws;       // xr1 -> h1 in place (N x 128); h2 reuses first N x 64
    unsigned short* xl1b = B + (long)N_ * 128;          // N x 128
    unsigned short* xl2b = xl1b + (long)N_ * 128;       // N x 64
    unsigned short* xr2b = xl2b + (long)N_ * 64;        // N x 64
    int* deg     = (int*)(xr2b + (long)N_ * 64);        // N
    int* rs      = deg + N_;                            // N+1
    int* cursor  = rs + N_ + 1;                         // N
    int* csr_src = cursor + N_;                         // E
    int* gstart  = csr_src + E_;                        // NG+1
    int* rs_part = gstart + NG + 1;                     // N
    int* blksum  = rs_part + N_;                        // 256
    unsigned short* h2 = B;

    const int nblk = (N_ + 255) / 256;   // 196 (must be <= 256)
    const int csh  = 391;                // blocks per shard: 391*256*8 > E

    // D1: zero degree counters
    hipMemsetAsync(deg, 0, (size_t)N_ * sizeof(int), stream);
    // D2: XCD-sharded count + graph bounds
    count_gbound_kernel<<<csh * 8 + nblk, 256, 0, stream>>>(ei, deg, batch, gstart,
                                                            E_, N_, csh);
    // D3/D4: device-wide scan
    scan_local_kernel<<<nblk, 256, 0, stream>>>(deg, rs_part, blksum, N_);
    scan_final_kernel<<<nblk, 256, 0, stream>>>(rs_part, blksum, rs, cursor, N_, E_, nblk);
    // D5: XCD-sharded scatter (CSR fill)
    scatter_kernel<<<csh * 8, 256, 0, stream>>>(ei, cursor, csr_src, E_, N_, csh);
    // D6: GEMM1 -> xl1 (bf16), xr1 (bf16)
    gemm1_kernel<<<(N_ + 7) / 8, 256, 0, stream>>>(x, Wl1, Wr1, xl1b, B, N_);
    // D7: GAT layer 1 (head-merged, all-bf16), h1 in place over B
    {
        int blocks = (int)(((long)N_ * 64 + 255) / 256);
        gat1_kernel<<<blocks, 256, 0, stream>>>(xl1b, B, att1, b1, rs, csr_src, N_);
    }
    // D8: GEMM2 -> xl2 (bf16), xr2 (bf16)
    gemm2_kernel<<<(N_ + 7) / 8, 128, 0, stream>>>(B, Wl2, Wr2, xl2b, xr2b, N_);
    // D9: GAT layer 2 (all-bf16) -> h2 (bf16)
    {
        int blocks = (int)(((long)N_ * 64 + 255) / 256);
        gat2_kernel<<<blocks, 256, 0, stream>>>(xl2b, xr2b, att2, b2, rs, csr_src, h2, N_);
    }
    // D10: segmented mean-pool + classifier
    pool_final_kernel<<<NG, 64, 0, stream>>>(h2, gstart, lin_w, lin_b, out);
}